// Round 8
// baseline (481.431 us; speedup 1.0000x reference)
//
#include <hip/hip_runtime.h>
#include <hip/hip_bf16.h>

#define NNODES 50000
#define MLP_HID 200
#define NB_SCAN 196   // ceil(NNODES/256)

typedef __attribute__((ext_vector_type(8))) short bf16x8;
typedef __attribute__((ext_vector_type(4))) float f32x4;

__device__ __forceinline__ unsigned short f2bf(float x){
    unsigned u = __float_as_uint(x);
    unsigned r = (u + 0x7fffu + ((u >> 16) & 1u)) >> 16;
    return (unsigned short)r;
}
__device__ __forceinline__ float bflo(unsigned u){ return __uint_as_float(u << 16); }
__device__ __forceinline__ float bfhi(unsigned u){ return __uint_as_float(u & 0xffff0000u); }

// ---------------- converts ----------------
__global__ __launch_bounds__(256) void conv_bf(const float* __restrict__ X,
                                               unsigned short* __restrict__ Y,
                                               long n){
    long i = ((long)blockIdx.x * 256 + threadIdx.x) * 4;
    if (i >= n) return;
    float4 v = *(const float4*)&X[i];
    ushort4 p;
    p.x = f2bf(v.x); p.y = f2bf(v.y); p.z = f2bf(v.z); p.w = f2bf(v.w);
    *(ushort4*)&Y[i] = p;
}

// W[K][256] -> WT[256][K] bf16
__global__ __launch_bounds__(256) void conv_wt(const float* __restrict__ W,
                                               unsigned short* __restrict__ WT,
                                               int K){
    int c = blockIdx.x;
    for (int k = threadIdx.x; k < K; k += 256)
        WT[(size_t)c * K + k] = f2bf(W[(size_t)k * 256 + c]);
}

// ---------------- MFMA GEMM + attn-dot epilogue ------------------------------
// h[M x 256] = A[M x K] @ W[K x 256]; WT is [256][K]. One wave -> 16 rows x 256 cols.
template<int K>
__global__ __launch_bounds__(256) void mfma_gemm_attn(
    const unsigned short* __restrict__ Abf,
    const unsigned short* __restrict__ WT,
    const float* __restrict__ al, const float* __restrict__ ar,
    unsigned short* __restrict__ hb,
    float* __restrict__ el, float* __restrict__ er, int M)
{
    const int wv = threadIdx.x >> 6, lane = threadIdx.x & 63;
    const int r0 = blockIdx.x * 64 + wv * 16;
    const int l15 = lane & 15, ks = lane >> 4;

    f32x4 acc[16];
    #pragma unroll
    for (int nt = 0; nt < 16; nt++)
        #pragma unroll
        for (int q = 0; q < 4; q++) acc[nt][q] = 0.f;

    const int arow = min(r0 + l15, M - 1);
    const unsigned short* aptr = Abf + (size_t)arow * K + ks * 8;
    const unsigned short* bptr = WT + (size_t)l15 * K + ks * 8;

    #pragma unroll
    for (int k0 = 0; k0 < K; k0 += 32){
        bf16x8 a = *(const bf16x8*)(aptr + k0);
        #pragma unroll
        for (int nt = 0; nt < 16; nt++){
            bf16x8 b = *(const bf16x8*)(bptr + (size_t)nt * 16 * K + k0);
            acc[nt] = __builtin_amdgcn_mfma_f32_16x16x32_bf16(a, b, acc[nt], 0, 0, 0);
        }
    }

    // ---- el/er epilogue: value (nt,reg) = h[row=ks*4+reg][col=nt*16+l15] ----
    float elv[4][4], erv[4][4];
    #pragma unroll
    for (int r = 0; r < 4; r++)
        #pragma unroll
        for (int hh = 0; hh < 4; hh++){ elv[r][hh] = 0.f; erv[r][hh] = 0.f; }

    #pragma unroll
    for (int nt = 0; nt < 16; nt++){
        int col = nt * 16 + l15;
        float alv = al[col], arv = ar[col];
        #pragma unroll
        for (int reg = 0; reg < 4; reg++){
            elv[reg][nt >> 2] = fmaf(acc[nt][reg], alv, elv[reg][nt >> 2]);
            erv[reg][nt >> 2] = fmaf(acc[nt][reg], arv, erv[reg][nt >> 2]);
        }
    }
    #pragma unroll
    for (int o = 8; o > 0; o >>= 1){
        #pragma unroll
        for (int reg = 0; reg < 4; reg++)
            #pragma unroll
            for (int hh = 0; hh < 4; hh++){
                elv[reg][hh] += __shfl_xor(elv[reg][hh], o);
                erv[reg][hh] += __shfl_xor(erv[reg][hh], o);
            }
    }
    if (l15 == 0){
        #pragma unroll
        for (int reg = 0; reg < 4; reg++){
            int r = r0 + ks * 4 + reg;
            if (r < M){
                #pragma unroll
                for (int hh = 0; hh < 4; hh++){
                    el[r * 4 + hh] = elv[reg][hh];
                    er[r * 4 + hh] = erv[reg][hh];
                }
            }
        }
    }

    // ---- bf16 h store via per-wave LDS repack ----
    __shared__ __align__(16) unsigned short hbuf[4][16][264];
    #pragma unroll
    for (int nt = 0; nt < 16; nt++)
        #pragma unroll
        for (int reg = 0; reg < 4; reg++)
            hbuf[wv][ks * 4 + reg][nt * 16 + l15] = f2bf(acc[nt][reg]);
    #pragma unroll
    for (int t = 0; t < 8; t++){
        int chunk = t * 64 + lane;       // 0..511
        int rr = chunk >> 5;             // 0..15
        int cc = (chunk & 31) * 8;       // 0..248
        int r = r0 + rr;
        if (r < M){
            uint4 v = *(const uint4*)&hbuf[wv][rr][cc];
            *(uint4*)&hb[(size_t)r * 256 + cc] = v;
        }
    }
}

// ---------------- plain f32 GEMM (MLP layer): +bias +relu --------------------
template<int KT, bool RELU>
__global__ __launch_bounds__(256) void gemm_tile(const float* __restrict__ A,
                                                 const float* __restrict__ B,
                                                 const float* __restrict__ bias,
                                                 float* __restrict__ C,
                                                 int M, int Nc){
    __shared__ float As[16][64];
    __shared__ float Bs[16][64];
    const int tid = threadIdx.x;
    const int tx = tid & 15, ty = tid >> 4;
    const int r0 = blockIdx.y * 64, c0 = blockIdx.x * 64;
    float acc[4][4] = {};
    const int lr  = tid >> 2,  lk4 = (tid & 3) * 4;
    const int bk  = tid >> 4,  bc4 = (tid & 15) * 4;

    for (int k0 = 0; k0 < KT; k0 += 16){
        float4 av = make_float4(0.f,0.f,0.f,0.f);
        if (r0 + lr < M) av = *(const float4*)&A[(size_t)(r0 + lr) * KT + k0 + lk4];
        As[lk4+0][lr] = av.x; As[lk4+1][lr] = av.y;
        As[lk4+2][lr] = av.z; As[lk4+3][lr] = av.w;

        if (c0 + bc4 + 3 < Nc){
            float4 bv = *(const float4*)&B[(size_t)(k0 + bk) * Nc + c0 + bc4];
            Bs[bk][bc4+0] = bv.x; Bs[bk][bc4+1] = bv.y;
            Bs[bk][bc4+2] = bv.z; Bs[bk][bc4+3] = bv.w;
        } else {
            #pragma unroll
            for (int j = 0; j < 4; j++){
                int c = c0 + bc4 + j;
                Bs[bk][bc4+j] = (c < Nc) ? B[(size_t)(k0 + bk) * Nc + c] : 0.f;
            }
        }
        __syncthreads();
        #pragma unroll
        for (int kk = 0; kk < 16; kk++){
            float4 a = *(const float4*)&As[kk][ty*4];
            float4 b = *(const float4*)&Bs[kk][tx*4];
            float arr[4] = {a.x,a.y,a.z,a.w};
            float brr[4] = {b.x,b.y,b.z,b.w};
            #pragma unroll
            for (int i = 0; i < 4; i++)
                #pragma unroll
                for (int j = 0; j < 4; j++)
                    acc[i][j] = fmaf(arr[i], brr[j], acc[i][j]);
        }
        __syncthreads();
    }
    #pragma unroll
    for (int i = 0; i < 4; i++){
        int r = r0 + ty*4 + i;
        if (r >= M) continue;
        #pragma unroll
        for (int j = 0; j < 4; j++){
            int c = c0 + tx*4 + j;
            if (c >= Nc) continue;
            float v = acc[i][j];
            if (bias) v += bias[c];
            if (RELU) v = fmaxf(v, 0.f);
            C[(size_t)r * Nc + c] = v;
        }
    }
}

// ---------------- CSR build (hierarchical scan) ----------------
__global__ __launch_bounds__(256) void csr_count(const int* __restrict__ dst,
                                                 int* __restrict__ cnt, int E){
    int e = blockIdx.x * blockDim.x + threadIdx.x;
    if (e < E) atomicAdd(&cnt[dst[e]], 1);
}

__global__ __launch_bounds__(256) void csr_bsum(const int* __restrict__ cnt,
                                                int* __restrict__ bsum){
    __shared__ int red[256];
    int i = blockIdx.x * 256 + threadIdx.x;
    red[threadIdx.x] = (i < NNODES) ? cnt[i] : 0;
    __syncthreads();
    for (int off = 128; off > 0; off >>= 1){
        if (threadIdx.x < off) red[threadIdx.x] += red[threadIdx.x + off];
        __syncthreads();
    }
    if (threadIdx.x == 0) bsum[blockIdx.x] = red[0];
}

__global__ __launch_bounds__(256) void csr_bscan(const int* __restrict__ bsum,
                                                 int* __restrict__ boff){
    __shared__ int part[256];
    int t = threadIdx.x;
    int v = (t < NB_SCAN) ? bsum[t] : 0;
    part[t] = v;
    __syncthreads();
    for (int off = 1; off < 256; off <<= 1){
        int u = (t >= off) ? part[t - off] : 0;
        __syncthreads();
        part[t] += u;
        __syncthreads();
    }
    if (t < NB_SCAN) boff[t] = part[t] - v;   // exclusive
}

__global__ __launch_bounds__(256) void csr_fill(const int* __restrict__ cnt,
                                                const int* __restrict__ boff,
                                                int* __restrict__ row_ptr,
                                                int* __restrict__ cursor){
    __shared__ int part[256];
    int b = blockIdx.x, t = threadIdx.x;
    int i = b * 256 + t;
    int c = (i < NNODES) ? cnt[i] : 0;
    part[t] = c;
    __syncthreads();
    for (int off = 1; off < 256; off <<= 1){
        int u = (t >= off) ? part[t - off] : 0;
        __syncthreads();
        part[t] += u;
        __syncthreads();
    }
    int excl = part[t] - c + boff[b];
    if (i < NNODES){ row_ptr[i] = excl; cursor[i] = excl; }
    if (i == NNODES - 1) row_ptr[NNODES] = excl + c;
}

__global__ __launch_bounds__(256) void csr_scatter(const int* __restrict__ src,
                                                   const int* __restrict__ dst,
                                                   int* __restrict__ cursor,
                                                   int* __restrict__ col_src, int E){
    int e = blockIdx.x * blockDim.x + threadIdx.x;
    if (e >= E) return;
    int pos = atomicAdd(&cursor[dst[e]], 1);
    col_src[pos] = src[e];
}

// ---------------- fused edge softmax + wide gather + epilogue (v4) -----------
// Single-pass softmax: e bounded (~|2|) so exp(e)/sum(exp(e)) is safe without
// max subtraction (identical math). Weights+indices cached in LDS; normalize
// folded into one post-loop accumulator scale.
__global__ __launch_bounds__(256) void gat_edge_v4(
    const int* __restrict__ row_ptr, const int* __restrict__ col_src,
    const float* __restrict__ el, const float* __restrict__ er,
    const unsigned short* __restrict__ hb, const float* __restrict__ bias,
    float* __restrict__ out_f, unsigned short* __restrict__ out_b)
{
    __shared__ float s_inv[4], s_er[4];
    __shared__ int   s_idx[512];
    __shared__ float s_w[512][4];
    __shared__ __align__(16) float s_red[8][264];
    __shared__ float s_val[256];

    const int n = blockIdx.x;
    const int tid = threadIdx.x;
    const int lane = tid & 63;
    const int h = tid >> 6;
    const int rs = row_ptr[n], re = row_ptr[n + 1];
    const int K = re - rs;
    const float er_h = er[n * 4 + h];

    // phase 1: single pass — w = exp(leaky(el+er)), cache w & idx, sum
    float ls = 0.f;
    for (int k = lane; k < K; k += 64){
        int s = col_src[rs + k];
        float e = el[s * 4 + h] + er_h;
        e = (e >= 0.f) ? e : 0.2f * e;
        float w = __expf(e);
        if (k < 512){
            s_w[k][h] = w;
            if (h == 0) s_idx[k] = s;
        }
        ls += w;
    }
    #pragma unroll
    for (int o = 32; o > 0; o >>= 1) ls += __shfl_xor(ls, o);
    if (lane == 0){ s_inv[h] = 1.f / ls; s_er[h] = er_h; }
    __syncthreads();

    // phase 2: chunked wide gather (8 slots x 32 threads x 8 dims, 16B loads)
    float acc[8];
    #pragma unroll
    for (int q = 0; q < 8; q++) acc[q] = 0.f;
    const int slot = tid >> 5;            // 0..7 edge slot
    const int c8   = (tid & 31) * 8;      // dim chunk
    const int hc   = c8 >> 6;             // head of this chunk

    for (int kc = 0; kc < K; kc += 512){
        if (kc > 0){                      // rare fallback: refill cache
            __syncthreads();
            int kend = min(K, kc + 512);
            for (int k = kc + lane; k < kend; k += 64){
                int s = col_src[rs + k];
                float e = el[s * 4 + h] + s_er[h];
                e = (e >= 0.f) ? e : 0.2f * e;
                s_w[k - kc][h] = __expf(e);
                if (h == 0) s_idx[k - kc] = s;
            }
            __syncthreads();
        }
        int rem = min(512, K - kc);
        for (int j = slot; j < rem; j += 8){
            int sN = s_idx[j];
            float w = s_w[j][hc];
            uint4 v = *(const uint4*)&hb[(size_t)sN * 256 + c8];
            acc[0] = fmaf(w, bflo(v.x), acc[0]);
            acc[1] = fmaf(w, bfhi(v.x), acc[1]);
            acc[2] = fmaf(w, bflo(v.y), acc[2]);
            acc[3] = fmaf(w, bfhi(v.y), acc[3]);
            acc[4] = fmaf(w, bflo(v.z), acc[4]);
            acc[5] = fmaf(w, bfhi(v.z), acc[5]);
            acc[6] = fmaf(w, bflo(v.w), acc[6]);
            acc[7] = fmaf(w, bfhi(v.w), acc[7]);
        }
    }
    const float invh = s_inv[hc];
    #pragma unroll
    for (int q = 0; q < 8; q++) acc[q] *= invh;

    // reduce across 8 slots
    *(float4*)&s_red[slot][c8]     = make_float4(acc[0], acc[1], acc[2], acc[3]);
    *(float4*)&s_red[slot][c8 + 4] = make_float4(acc[4], acc[5], acc[6], acc[7]);
    __syncthreads();
    {
        int d = tid;                      // 0..255 output dim
        float v = 0.f;
        #pragma unroll
        for (int j = 0; j < 8; j++) v += s_red[j][d];
        v = fmaxf(v + bias[d], 0.f);
        s_val[d] = v;
    }
    __syncthreads();
    if (tid < 64){
        float m = (s_val[tid] + s_val[tid + 64] + s_val[tid + 128] + s_val[tid + 192]) * 0.25f;
        out_f[(size_t)n * 64 + tid] = m;
        out_b[(size_t)n * 64 + tid] = f2bf(m);
    }
}

// ---------------- BN stats ---------------------------------------------------
__global__ __launch_bounds__(256) void bn_stats(const float* __restrict__ z,
                                                float* __restrict__ bsum,
                                                float* __restrict__ bsumsq,
                                                int Nrows){
    int col = threadIdx.x;
    if (col >= MLP_HID) return;
    int r0 = blockIdx.x * 256;
    int r1 = min(r0 + 256, Nrows);
    float s = 0.f, ss = 0.f;
    for (int r = r0; r < r1; r++){
        float v = z[(size_t)r * MLP_HID + col];
        s += v; ss += v * v;
    }
    atomicAdd(&bsum[col], s);
    atomicAdd(&bsumsq[col], ss);
}

__global__ void bn_final(const float* __restrict__ bsum,
                         const float* __restrict__ bsumsq,
                         const float* __restrict__ gamma,
                         const float* __restrict__ beta,
                         float* __restrict__ scale,
                         float* __restrict__ shift,
                         int Nrows){
    int col = threadIdx.x;
    if (col >= MLP_HID) return;
    float inv = 1.f / (float)Nrows;
    float mu = bsum[col] * inv;
    float var = bsumsq[col] * inv - mu * mu;
    float rstd = rsqrtf(var + 1e-5f);
    float sc = rstd * gamma[col];
    scale[col] = sc;
    shift[col] = beta[col] - mu * sc;
}

// ---------------- final linear ----------------------------------------------
__global__ __launch_bounds__(256) void mlp2(const float* __restrict__ z,
                                            const float* __restrict__ scale,
                                            const float* __restrict__ shift,
                                            const float* __restrict__ Wm2,
                                            const float* __restrict__ bm2,
                                            float* __restrict__ out,
                                            int Nrows){
    int g = blockIdx.x * blockDim.x + threadIdx.x;
    int n = g >> 6;
    if (n >= Nrows) return;
    int lane = threadIdx.x & 63;
    float a0 = 0.f, a1 = 0.f;
    for (int k = lane; k < MLP_HID; k += 64){
        float zn = z[(size_t)n * MLP_HID + k] * scale[k] + shift[k];
        a0 = fmaf(zn, Wm2[k * 2 + 0], a0);
        a1 = fmaf(zn, Wm2[k * 2 + 1], a1);
    }
    #pragma unroll
    for (int o = 32; o > 0; o >>= 1){
        a0 += __shfl_xor(a0, o);
        a1 += __shfl_xor(a1, o);
    }
    if (lane == 0){
        out[n * 2 + 0] = a0 + bm2[0];
        out[n * 2 + 1] = a1 + bm2[1];
    }
}

extern "C" void kernel_launch(void* const* d_in, const int* in_sizes, int n_in,
                              void* d_out, int out_size, void* d_ws, size_t ws_size,
                              hipStream_t stream) {
    const float* feat  = (const float*)d_in[0];
    const int*   src   = (const int*)  d_in[1];
    const int*   dst   = (const int*)  d_in[2];
    const float* W1    = (const float*)d_in[3];
    const float* al1   = (const float*)d_in[4];
    const float* ar1   = (const float*)d_in[5];
    const float* b1    = (const float*)d_in[6];
    const float* W2    = (const float*)d_in[7];
    const float* al2   = (const float*)d_in[8];
    const float* ar2   = (const float*)d_in[9];
    const float* b2    = (const float*)d_in[10];
    const float* Wm1   = (const float*)d_in[11];
    const float* bm1   = (const float*)d_in[12];
    const float* gamma = (const float*)d_in[13];
    const float* beta  = (const float*)d_in[14];
    const float* Wm2   = (const float*)d_in[15];
    const float* bm2   = (const float*)d_in[16];
    const int E = in_sizes[1];
    float* out = (float*)d_out;

    // ---- workspace layout ----
    unsigned short* h_bf   = (unsigned short*)d_ws;                 // N*256 bf16
    unsigned short* featbf = h_bf   + (size_t)NNODES * 256;         // N*128 bf16 (dead after L1 gemm)
    unsigned short* o1_bf  = featbf + (size_t)NNODES * 128;         // N*64 bf16
    unsigned short* o2_bf  = o1_bf  + (size_t)NNODES * 64;          // N*64 bf16
    unsigned short* W1T    = o2_bf  + (size_t)NNODES * 64;          // 256*128
    unsigned short* W2T    = W1T + 256 * 128;                       // 256*64
    float* z      = (float*)(W2T + 256 * 64);                       // N*200 f32
    float* o1_f   = z      + (size_t)NNODES * MLP_HID;              // N*64 f32 (scratch)
    float* el     = o1_f   + (size_t)NNODES * 64;                   // N*4
    float* er     = el     + (size_t)NNODES * 4;                    // N*4
    float* bn_sum   = er + (size_t)NNODES * 4;                      // 200
    float* bn_sumsq = bn_sum + MLP_HID;                             // 200
    float* bn_scale = bn_sumsq + MLP_HID;                           // 200
    float* bn_shift = bn_scale + MLP_HID;                           // 200
    int* cnt      = (int*)(bn_shift + MLP_HID);                     // N
    int* row_ptr  = cnt + NNODES;                                   // N+1
    int* cursor   = row_ptr + NNODES + 1;                           // N
    int* bsum     = cursor + NNODES;                                // 256
    int* boff     = bsum + 256;                                     // 256
    int* col_src  = boff + 256;                                     // E
    float* out2_f = (float*)featbf;   // alias: featbf dead after layer-1 GEMM

    const dim3 blk(256);
    const int eg = (E + 255) / 256;
    const int gb = (NNODES + 63) / 64;

    // ---- conversions ----
    conv_bf<<<(int)(((long)NNODES * 128 / 4 + 255) / 256), blk, 0, stream>>>(
        feat, featbf, (long)NNODES * 128);
    conv_wt<<<256, blk, 0, stream>>>(W1, W1T, 128);
    conv_wt<<<256, blk, 0, stream>>>(W2, W2T, 64);

    // ---- CSR build ----
    hipMemsetAsync(cnt, 0, NNODES * 4, stream);
    csr_count<<<eg, blk, 0, stream>>>(dst, cnt, E);
    csr_bsum<<<NB_SCAN, blk, 0, stream>>>(cnt, bsum);
    csr_bscan<<<1, blk, 0, stream>>>(bsum, boff);
    csr_fill<<<NB_SCAN, blk, 0, stream>>>(cnt, boff, row_ptr, cursor);
    csr_scatter<<<eg, blk, 0, stream>>>(src, dst, cursor, col_src, E);

    // ---- layer 1 ----
    mfma_gemm_attn<128><<<gb, blk, 0, stream>>>(featbf, W1T, al1, ar1, h_bf, el, er, NNODES);
    gat_edge_v4<<<NNODES, blk, 0, stream>>>(row_ptr, col_src, el, er, h_bf, b1,
                                            o1_f, o1_bf);

    // ---- layer 2 ----
    mfma_gemm_attn<64><<<gb, blk, 0, stream>>>(o1_bf, W2T, al2, ar2, h_bf, el, er, NNODES);
    gat_edge_v4<<<NNODES, blk, 0, stream>>>(row_ptr, col_src, el, er, h_bf, b2,
                                            out2_f, o2_bf);

    // ---- MLP (f32 for BN-amplified accuracy) ----
    gemm_tile<64,true><<<dim3((MLP_HID + 63) / 64, gb), blk, 0, stream>>>(
        out2_f, Wm1, bm1, z, NNODES, MLP_HID);

    hipMemsetAsync(bn_sum, 0, 2 * MLP_HID * 4, stream);
    bn_stats<<<(NNODES + 255) / 256, blk, 0, stream>>>(z, bn_sum, bn_sumsq, NNODES);
    bn_final<<<1, 256, 0, stream>>>(bn_sum, bn_sumsq, gamma, beta, bn_scale, bn_shift, NNODES);
    mlp2<<<(NNODES * 64 + 255) / 256, blk, 0, stream>>>(
        z, bn_scale, bn_shift, Wm2, bm2, out, NNODES);
}

// Round 9
// 427.360 us; speedup vs baseline: 1.1265x; 1.1265x over previous
//
#include <hip/hip_runtime.h>
#include <hip/hip_bf16.h>

#define NNODES 50000
#define MLP_HID 200
#define NB_SCAN 196   // ceil(NNODES/256)

// init mega-kernel block ranges
#define NB_CONV 6250          // N*128/4/256
#define NB_W1   256
#define NB_W2   256
#define NB_ZC   196
#define INIT_BLOCKS (NB_CONV + NB_W1 + NB_W2 + NB_ZC + 1)

typedef __attribute__((ext_vector_type(8))) short bf16x8;
typedef __attribute__((ext_vector_type(4))) float f32x4;

__device__ __forceinline__ unsigned short f2bf(float x){
    unsigned u = __float_as_uint(x);
    unsigned r = (u + 0x7fffu + ((u >> 16) & 1u)) >> 16;
    return (unsigned short)r;
}
__device__ __forceinline__ float bflo(unsigned u){ return __uint_as_float(u << 16); }
__device__ __forceinline__ float bfhi(unsigned u){ return __uint_as_float(u & 0xffff0000u); }

// ---------------- init: feat->bf16, W1T, W2T, zero cnt & bn accumulators -----
__global__ __launch_bounds__(256) void init_all(
    const float* __restrict__ feat, unsigned short* __restrict__ featbf,
    const float* __restrict__ W1, unsigned short* __restrict__ W1T,
    const float* __restrict__ W2, unsigned short* __restrict__ W2T,
    int* __restrict__ cnt, float* __restrict__ bn_acc /*400 floats*/)
{
    const int b = blockIdx.x, tid = threadIdx.x;
    if (b < NB_CONV){
        long i = ((long)b * 256 + tid) * 4;
        float4 v = *(const float4*)&feat[i];
        ushort4 p;
        p.x = f2bf(v.x); p.y = f2bf(v.y); p.z = f2bf(v.z); p.w = f2bf(v.w);
        *(ushort4*)&featbf[i] = p;
    } else if (b < NB_CONV + NB_W1){
        int c = b - NB_CONV;
        if (tid < 128) W1T[(size_t)c * 128 + tid] = f2bf(W1[(size_t)tid * 256 + c]);
    } else if (b < NB_CONV + NB_W1 + NB_W2){
        int c = b - NB_CONV - NB_W1;
        if (tid < 64) W2T[(size_t)c * 64 + tid] = f2bf(W2[(size_t)tid * 256 + c]);
    } else if (b < NB_CONV + NB_W1 + NB_W2 + NB_ZC){
        int i = (b - NB_CONV - NB_W1 - NB_W2) * 256 + tid;
        if (i < NNODES) cnt[i] = 0;
    } else {
        if (tid < 2 * MLP_HID - 256) bn_acc[256 + tid] = 0.f;
        bn_acc[tid] = 0.f;
    }
}

// ---------------- MFMA GEMM + attn-dot epilogue ------------------------------
template<int K>
__global__ __launch_bounds__(256) void mfma_gemm_attn(
    const unsigned short* __restrict__ Abf,
    const unsigned short* __restrict__ WT,
    const float* __restrict__ al, const float* __restrict__ ar,
    unsigned short* __restrict__ hb,
    float* __restrict__ el, float* __restrict__ er, int M)
{
    const int wv = threadIdx.x >> 6, lane = threadIdx.x & 63;
    const int r0 = blockIdx.x * 64 + wv * 16;
    const int l15 = lane & 15, ks = lane >> 4;

    f32x4 acc[16];
    #pragma unroll
    for (int nt = 0; nt < 16; nt++)
        #pragma unroll
        for (int q = 0; q < 4; q++) acc[nt][q] = 0.f;

    const int arow = min(r0 + l15, M - 1);
    const unsigned short* aptr = Abf + (size_t)arow * K + ks * 8;
    const unsigned short* bptr = WT + (size_t)l15 * K + ks * 8;

    #pragma unroll
    for (int k0 = 0; k0 < K; k0 += 32){
        bf16x8 a = *(const bf16x8*)(aptr + k0);
        #pragma unroll
        for (int nt = 0; nt < 16; nt++){
            bf16x8 b = *(const bf16x8*)(bptr + (size_t)nt * 16 * K + k0);
            acc[nt] = __builtin_amdgcn_mfma_f32_16x16x32_bf16(a, b, acc[nt], 0, 0, 0);
        }
    }

    float elv[4][4], erv[4][4];
    #pragma unroll
    for (int r = 0; r < 4; r++)
        #pragma unroll
        for (int hh = 0; hh < 4; hh++){ elv[r][hh] = 0.f; erv[r][hh] = 0.f; }

    #pragma unroll
    for (int nt = 0; nt < 16; nt++){
        int col = nt * 16 + l15;
        float alv = al[col], arv = ar[col];
        #pragma unroll
        for (int reg = 0; reg < 4; reg++){
            elv[reg][nt >> 2] = fmaf(acc[nt][reg], alv, elv[reg][nt >> 2]);
            erv[reg][nt >> 2] = fmaf(acc[nt][reg], arv, erv[reg][nt >> 2]);
        }
    }
    #pragma unroll
    for (int o = 8; o > 0; o >>= 1){
        #pragma unroll
        for (int reg = 0; reg < 4; reg++)
            #pragma unroll
            for (int hh = 0; hh < 4; hh++){
                elv[reg][hh] += __shfl_xor(elv[reg][hh], o);
                erv[reg][hh] += __shfl_xor(erv[reg][hh], o);
            }
    }
    if (l15 == 0){
        #pragma unroll
        for (int reg = 0; reg < 4; reg++){
            int r = r0 + ks * 4 + reg;
            if (r < M){
                #pragma unroll
                for (int hh = 0; hh < 4; hh++){
                    el[r * 4 + hh] = elv[reg][hh];
                    er[r * 4 + hh] = erv[reg][hh];
                }
            }
        }
    }

    __shared__ __align__(16) unsigned short hbuf[4][16][264];
    #pragma unroll
    for (int nt = 0; nt < 16; nt++)
        #pragma unroll
        for (int reg = 0; reg < 4; reg++)
            hbuf[wv][ks * 4 + reg][nt * 16 + l15] = f2bf(acc[nt][reg]);
    #pragma unroll
    for (int t = 0; t < 8; t++){
        int chunk = t * 64 + lane;
        int rr = chunk >> 5;
        int cc = (chunk & 31) * 8;
        int r = r0 + rr;
        if (r < M){
            uint4 v = *(const uint4*)&hbuf[wv][rr][cc];
            *(uint4*)&hb[(size_t)r * 256 + cc] = v;
        }
    }
}

// ---------------- f32 GEMM (MLP layer): +bias +relu, fused BN partials -------
template<int KT, bool RELU, bool BN>
__global__ __launch_bounds__(256) void gemm_tile(const float* __restrict__ A,
                                                 const float* __restrict__ B,
                                                 const float* __restrict__ bias,
                                                 float* __restrict__ C,
                                                 float* __restrict__ bn_sum,
                                                 float* __restrict__ bn_sumsq,
                                                 int M, int Nc){
    __shared__ float As[16][64];
    __shared__ float Bs[16][64];
    __shared__ float bnred[16][64];
    const int tid = threadIdx.x;
    const int tx = tid & 15, ty = tid >> 4;
    const int r0 = blockIdx.y * 64, c0 = blockIdx.x * 64;
    float acc[4][4] = {};
    const int lr  = tid >> 2,  lk4 = (tid & 3) * 4;
    const int bk  = tid >> 4,  bc4 = (tid & 15) * 4;

    for (int k0 = 0; k0 < KT; k0 += 16){
        float4 av = make_float4(0.f,0.f,0.f,0.f);
        if (r0 + lr < M) av = *(const float4*)&A[(size_t)(r0 + lr) * KT + k0 + lk4];
        As[lk4+0][lr] = av.x; As[lk4+1][lr] = av.y;
        As[lk4+2][lr] = av.z; As[lk4+3][lr] = av.w;

        if (c0 + bc4 + 3 < Nc){
            float4 bv = *(const float4*)&B[(size_t)(k0 + bk) * Nc + c0 + bc4];
            Bs[bk][bc4+0] = bv.x; Bs[bk][bc4+1] = bv.y;
            Bs[bk][bc4+2] = bv.z; Bs[bk][bc4+3] = bv.w;
        } else {
            #pragma unroll
            for (int j = 0; j < 4; j++){
                int c = c0 + bc4 + j;
                Bs[bk][bc4+j] = (c < Nc) ? B[(size_t)(k0 + bk) * Nc + c] : 0.f;
            }
        }
        __syncthreads();
        #pragma unroll
        for (int kk = 0; kk < 16; kk++){
            float4 a = *(const float4*)&As[kk][ty*4];
            float4 b = *(const float4*)&Bs[kk][tx*4];
            float arr[4] = {a.x,a.y,a.z,a.w};
            float brr[4] = {b.x,b.y,b.z,b.w};
            #pragma unroll
            for (int i = 0; i < 4; i++)
                #pragma unroll
                for (int j = 0; j < 4; j++)
                    acc[i][j] = fmaf(arr[i], brr[j], acc[i][j]);
        }
        __syncthreads();
    }

    float cs[4] = {0,0,0,0}, css[4] = {0,0,0,0};
    #pragma unroll
    for (int i = 0; i < 4; i++){
        int r = r0 + ty*4 + i;
        bool rok = r < M;
        #pragma unroll
        for (int j = 0; j < 4; j++){
            int c = c0 + tx*4 + j;
            if (c >= Nc) continue;
            float v = acc[i][j];
            if (bias) v += bias[c];
            if (RELU) v = fmaxf(v, 0.f);
            if (rok){
                C[(size_t)r * Nc + c] = v;
                if (BN){ cs[j] += v; css[j] += v * v; }
            }
        }
    }
    if (BN){
        #pragma unroll
        for (int j = 0; j < 4; j++) bnred[ty][tx*4+j] = cs[j];
        __syncthreads();
        if (tid < 64){
            float s = 0.f;
            #pragma unroll
            for (int t = 0; t < 16; t++) s += bnred[t][tid];
            if (c0 + tid < Nc) atomicAdd(&bn_sum[c0 + tid], s);
        }
        __syncthreads();
        #pragma unroll
        for (int j = 0; j < 4; j++) bnred[ty][tx*4+j] = css[j];
        __syncthreads();
        if (tid < 64){
            float s = 0.f;
            #pragma unroll
            for (int t = 0; t < 16; t++) s += bnred[t][tid];
            if (c0 + tid < Nc) atomicAdd(&bn_sumsq[c0 + tid], s);
        }
    }
}

// ---------------- CSR build (hierarchical scan) ----------------
__global__ __launch_bounds__(256) void csr_count(const int* __restrict__ dst,
                                                 int* __restrict__ cnt, int E){
    int e = blockIdx.x * blockDim.x + threadIdx.x;
    if (e < E) atomicAdd(&cnt[dst[e]], 1);
}

__global__ __launch_bounds__(256) void csr_bsum(const int* __restrict__ cnt,
                                                int* __restrict__ bsum){
    __shared__ int red[256];
    int i = blockIdx.x * 256 + threadIdx.x;
    red[threadIdx.x] = (i < NNODES) ? cnt[i] : 0;
    __syncthreads();
    for (int off = 128; off > 0; off >>= 1){
        if (threadIdx.x < off) red[threadIdx.x] += red[threadIdx.x + off];
        __syncthreads();
    }
    if (threadIdx.x == 0) bsum[blockIdx.x] = red[0];
}

__global__ __launch_bounds__(256) void csr_bscan(const int* __restrict__ bsum,
                                                 int* __restrict__ boff){
    __shared__ int part[256];
    int t = threadIdx.x;
    int v = (t < NB_SCAN) ? bsum[t] : 0;
    part[t] = v;
    __syncthreads();
    for (int off = 1; off < 256; off <<= 1){
        int u = (t >= off) ? part[t - off] : 0;
        __syncthreads();
        part[t] += u;
        __syncthreads();
    }
    if (t < NB_SCAN) boff[t] = part[t] - v;
}

__global__ __launch_bounds__(256) void csr_fill(const int* __restrict__ cnt,
                                                const int* __restrict__ boff,
                                                int* __restrict__ row_ptr,
                                                int* __restrict__ cursor){
    __shared__ int part[256];
    int b = blockIdx.x, t = threadIdx.x;
    int i = b * 256 + t;
    int c = (i < NNODES) ? cnt[i] : 0;
    part[t] = c;
    __syncthreads();
    for (int off = 1; off < 256; off <<= 1){
        int u = (t >= off) ? part[t - off] : 0;
        __syncthreads();
        part[t] += u;
        __syncthreads();
    }
    int excl = part[t] - c + boff[b];
    if (i < NNODES){ row_ptr[i] = excl; cursor[i] = excl; }
    if (i == NNODES - 1) row_ptr[NNODES] = excl + c;
}

__global__ __launch_bounds__(256) void csr_scatter(const int* __restrict__ src,
                                                   const int* __restrict__ dst,
                                                   int* __restrict__ cursor,
                                                   int* __restrict__ col_src, int E){
    int e = blockIdx.x * blockDim.x + threadIdx.x;
    if (e >= E) return;
    int pos = atomicAdd(&cursor[dst[e]], 1);
    col_src[pos] = src[e];
}

// ---------------- fused edge softmax + wide gather + epilogue (v5) -----------
// Phase 1: k-split over 256 threads, one float4 el-load per edge covers all 4
// heads; weights to conflict-free s_w[4][512]. Phase 2: 8 slots x 32 x 8dims,
// 2-deep unrolled 16B gathers; slot-pair shfl merge, LDS reduce, head-mean.
__global__ __launch_bounds__(256) void gat_edge_v5(
    const int* __restrict__ row_ptr, const int* __restrict__ col_src,
    const float* __restrict__ el, const float* __restrict__ er,
    const unsigned short* __restrict__ hb, const float* __restrict__ bias,
    float* __restrict__ out_f, unsigned short* __restrict__ out_b)
{
    __shared__ float s_w[4][512];
    __shared__ int   s_idx[512];
    __shared__ float s_part[4][4];
    __shared__ float s_inv[4];
    __shared__ __align__(16) float s_red[4][264];
    __shared__ float s_val[256];

    const int n = blockIdx.x;
    const int tid = threadIdx.x;
    const int lane = tid & 63;
    const int wv = tid >> 6;
    const int rs = row_ptr[n], re = row_ptr[n + 1];
    const int K = re - rs;
    const float4 ern = *(const float4*)&er[n * 4];

    // phase 1
    float ls0 = 0.f, ls1 = 0.f, ls2 = 0.f, ls3 = 0.f;
    for (int k = tid; k < K; k += 256){
        int s = col_src[rs + k];
        float4 e4 = *(const float4*)&el[s * 4];
        float e0 = e4.x + ern.x; e0 = (e0 >= 0.f) ? e0 : 0.2f * e0;
        float e1 = e4.y + ern.y; e1 = (e1 >= 0.f) ? e1 : 0.2f * e1;
        float e2 = e4.z + ern.z; e2 = (e2 >= 0.f) ? e2 : 0.2f * e2;
        float e3 = e4.w + ern.w; e3 = (e3 >= 0.f) ? e3 : 0.2f * e3;
        float w0 = __expf(e0), w1 = __expf(e1), w2 = __expf(e2), w3 = __expf(e3);
        if (k < 512){
            s_idx[k] = s;
            s_w[0][k] = w0; s_w[1][k] = w1; s_w[2][k] = w2; s_w[3][k] = w3;
        }
        ls0 += w0; ls1 += w1; ls2 += w2; ls3 += w3;
    }
    #pragma unroll
    for (int o = 32; o > 0; o >>= 1){
        ls0 += __shfl_xor(ls0, o); ls1 += __shfl_xor(ls1, o);
        ls2 += __shfl_xor(ls2, o); ls3 += __shfl_xor(ls3, o);
    }
    if (lane == 0){
        s_part[wv][0] = ls0; s_part[wv][1] = ls1;
        s_part[wv][2] = ls2; s_part[wv][3] = ls3;
    }
    __syncthreads();
    if (tid < 4)
        s_inv[tid] = 1.f / (s_part[0][tid] + s_part[1][tid] + s_part[2][tid] + s_part[3][tid]);
    __syncthreads();

    // phase 2
    float acc[8];
    #pragma unroll
    for (int q = 0; q < 8; q++) acc[q] = 0.f;
    const int slot = tid >> 5;
    const int c8   = (tid & 31) * 8;
    const int hc   = c8 >> 6;

    for (int kc = 0; kc < K; kc += 512){
        if (kc > 0){                       // rare: refill cache for next chunk
            __syncthreads();
            int kend = min(K, kc + 512);
            for (int k = kc + tid; k < kend; k += 256){
                int s = col_src[rs + k];
                float4 e4 = *(const float4*)&el[s * 4];
                float e0 = e4.x + ern.x; e0 = (e0 >= 0.f) ? e0 : 0.2f * e0;
                float e1 = e4.y + ern.y; e1 = (e1 >= 0.f) ? e1 : 0.2f * e1;
                float e2 = e4.z + ern.z; e2 = (e2 >= 0.f) ? e2 : 0.2f * e2;
                float e3 = e4.w + ern.w; e3 = (e3 >= 0.f) ? e3 : 0.2f * e3;
                int kk = k - kc;
                s_idx[kk] = s;
                s_w[0][kk] = __expf(e0); s_w[1][kk] = __expf(e1);
                s_w[2][kk] = __expf(e2); s_w[3][kk] = __expf(e3);
            }
            __syncthreads();
        }
        int rem = min(512, K - kc);
        int j = slot;
        for (; j + 8 < rem; j += 16){
            int s0 = s_idx[j], s1 = s_idx[j + 8];
            float w0 = s_w[hc][j], w1 = s_w[hc][j + 8];
            uint4 v0 = *(const uint4*)&hb[(size_t)s0 * 256 + c8];
            uint4 v1 = *(const uint4*)&hb[(size_t)s1 * 256 + c8];
            acc[0] = fmaf(w0, bflo(v0.x), acc[0]);
            acc[1] = fmaf(w0, bfhi(v0.x), acc[1]);
            acc[2] = fmaf(w0, bflo(v0.y), acc[2]);
            acc[3] = fmaf(w0, bfhi(v0.y), acc[3]);
            acc[4] = fmaf(w0, bflo(v0.z), acc[4]);
            acc[5] = fmaf(w0, bfhi(v0.z), acc[5]);
            acc[6] = fmaf(w0, bflo(v0.w), acc[6]);
            acc[7] = fmaf(w0, bfhi(v0.w), acc[7]);
            acc[0] = fmaf(w1, bflo(v1.x), acc[0]);
            acc[1] = fmaf(w1, bfhi(v1.x), acc[1]);
            acc[2] = fmaf(w1, bflo(v1.y), acc[2]);
            acc[3] = fmaf(w1, bfhi(v1.y), acc[3]);
            acc[4] = fmaf(w1, bflo(v1.z), acc[4]);
            acc[5] = fmaf(w1, bfhi(v1.z), acc[5]);
            acc[6] = fmaf(w1, bflo(v1.w), acc[6]);
            acc[7] = fmaf(w1, bfhi(v1.w), acc[7]);
        }
        if (j < rem){
            int sN = s_idx[j];
            float w = s_w[hc][j];
            uint4 v = *(const uint4*)&hb[(size_t)sN * 256 + c8];
            acc[0] = fmaf(w, bflo(v.x), acc[0]);
            acc[1] = fmaf(w, bfhi(v.x), acc[1]);
            acc[2] = fmaf(w, bflo(v.y), acc[2]);
            acc[3] = fmaf(w, bfhi(v.y), acc[3]);
            acc[4] = fmaf(w, bflo(v.z), acc[4]);
            acc[5] = fmaf(w, bfhi(v.z), acc[5]);
            acc[6] = fmaf(w, bflo(v.w), acc[6]);
            acc[7] = fmaf(w, bfhi(v.w), acc[7]);
        }
    }
    const float invh = s_inv[hc];
    #pragma unroll
    for (int q = 0; q < 8; q++) acc[q] = acc[q] * invh + __shfl_xor(acc[q] * invh, 32);

    // lanes with (tid&32)==0 hold slot-pair sums -> s_red[slot>>1]
    if ((tid & 32) == 0){
        *(float4*)&s_red[slot >> 1][c8]     = make_float4(acc[0], acc[1], acc[2], acc[3]);
        *(float4*)&s_red[slot >> 1][c8 + 4] = make_float4(acc[4], acc[5], acc[6], acc[7]);
    }
    __syncthreads();
    {
        int d = tid;
        float v = s_red[0][d] + s_red[1][d] + s_red[2][d] + s_red[3][d];
        v = fmaxf(v + bias[d], 0.f);
        s_val[d] = v;
    }
    __syncthreads();
    if (tid < 64){
        float m = (s_val[tid] + s_val[tid + 64] + s_val[tid + 128] + s_val[tid + 192]) * 0.25f;
        if (out_f) out_f[(size_t)n * 64 + tid] = m;
        out_b[(size_t)n * 64 + tid] = f2bf(m);
    }
}

// ---------------- BN finalize ------------------------------------------------
__global__ void bn_final(const float* __restrict__ bsum,
                         const float* __restrict__ bsumsq,
                         const float* __restrict__ gamma,
                         const float* __restrict__ beta,
                         float* __restrict__ scale,
                         float* __restrict__ shift,
                         int Nrows){
    int col = threadIdx.x;
    if (col >= MLP_HID) return;
    float inv = 1.f / (float)Nrows;
    float mu = bsum[col] * inv;
    float var = bsumsq[col] * inv - mu * mu;
    float rstd = rsqrtf(var + 1e-5f);
    float sc = rstd * gamma[col];
    scale[col] = sc;
    shift[col] = beta[col] - mu * sc;
}

// ---------------- final linear ----------------------------------------------
__global__ __launch_bounds__(256) void mlp2(const float* __restrict__ z,
                                            const float* __restrict__ scale,
                                            const float* __restrict__ shift,
                                            const float* __restrict__ Wm2,
                                            const float* __restrict__ bm2,
                                            float* __restrict__ out,
                                            int Nrows){
    int g = blockIdx.x * blockDim.x + threadIdx.x;
    int n = g >> 6;
    if (n >= Nrows) return;
    int lane = threadIdx.x & 63;
    float a0 = 0.f, a1 = 0.f;
    for (int k = lane; k < MLP_HID; k += 64){
        float zn = z[(size_t)n * MLP_HID + k] * scale[k] + shift[k];
        a0 = fmaf(zn, Wm2[k * 2 + 0], a0);
        a1 = fmaf(zn, Wm2[k * 2 + 1], a1);
    }
    #pragma unroll
    for (int o = 32; o > 0; o >>= 1){
        a0 += __shfl_xor(a0, o);
        a1 += __shfl_xor(a1, o);
    }
    if (lane == 0){
        out[n * 2 + 0] = a0 + bm2[0];
        out[n * 2 + 1] = a1 + bm2[1];
    }
}

extern "C" void kernel_launch(void* const* d_in, const int* in_sizes, int n_in,
                              void* d_out, int out_size, void* d_ws, size_t ws_size,
                              hipStream_t stream) {
    const float* feat  = (const float*)d_in[0];
    const int*   src   = (const int*)  d_in[1];
    const int*   dst   = (const int*)  d_in[2];
    const float* W1    = (const float*)d_in[3];
    const float* al1   = (const float*)d_in[4];
    const float* ar1   = (const float*)d_in[5];
    const float* b1    = (const float*)d_in[6];
    const float* W2    = (const float*)d_in[7];
    const float* al2   = (const float*)d_in[8];
    const float* ar2   = (const float*)d_in[9];
    const float* b2    = (const float*)d_in[10];
    const float* Wm1   = (const float*)d_in[11];
    const float* bm1   = (const float*)d_in[12];
    const float* gamma = (const float*)d_in[13];
    const float* beta  = (const float*)d_in[14];
    const float* Wm2   = (const float*)d_in[15];
    const float* bm2   = (const float*)d_in[16];
    const int E = in_sizes[1];
    float* out = (float*)d_out;

    // ---- workspace layout ----
    unsigned short* h_bf   = (unsigned short*)d_ws;                 // N*256 bf16
    unsigned short* featbf = h_bf   + (size_t)NNODES * 256;         // N*128 bf16 (dead after L1 gemm)
    unsigned short* o1_bf  = featbf + (size_t)NNODES * 128;         // N*64 bf16
    unsigned short* o2_bf  = o1_bf  + (size_t)NNODES * 64;          // N*64 bf16
    unsigned short* W1T    = o2_bf  + (size_t)NNODES * 64;          // 256*128
    unsigned short* W2T    = W1T + 256 * 128;                       // 256*64
    float* z      = (float*)(W2T + 256 * 64);                       // N*200 f32
    float* el     = z      + (size_t)NNODES * MLP_HID;              // N*4
    float* er     = el     + (size_t)NNODES * 4;                    // N*4
    float* bn_sum   = er + (size_t)NNODES * 4;                      // 200
    float* bn_sumsq = bn_sum + MLP_HID;                             // 200
    float* bn_scale = bn_sumsq + MLP_HID;                           // 200
    float* bn_shift = bn_scale + MLP_HID;                           // 200
    int* cnt      = (int*)(bn_shift + MLP_HID);                     // N
    int* row_ptr  = cnt + NNODES;                                   // N+1
    int* cursor   = row_ptr + NNODES + 1;                           // N
    int* bsum     = cursor + NNODES;                                // 256
    int* boff     = bsum + 256;                                     // 256
    int* col_src  = boff + 256;                                     // E
    float* out2_f = (float*)featbf;   // alias: featbf dead after layer-1 GEMM

    const dim3 blk(256);
    const int eg = (E + 255) / 256;
    const int gb = (NNODES + 63) / 64;

    // ---- init (conversions + zeroing) ----
    init_all<<<INIT_BLOCKS, blk, 0, stream>>>(feat, featbf, W1, W1T, W2, W2T,
                                              cnt, bn_sum);

    // ---- CSR build ----
    csr_count<<<eg, blk, 0, stream>>>(dst, cnt, E);
    csr_bsum<<<NB_SCAN, blk, 0, stream>>>(cnt, bsum);
    csr_bscan<<<1, blk, 0, stream>>>(bsum, boff);
    csr_fill<<<NB_SCAN, blk, 0, stream>>>(cnt, boff, row_ptr, cursor);
    csr_scatter<<<eg, blk, 0, stream>>>(src, dst, cursor, col_src, E);

    // ---- layer 1 ----
    mfma_gemm_attn<128><<<gb, blk, 0, stream>>>(featbf, W1T, al1, ar1, h_bf, el, er, NNODES);
    gat_edge_v5<<<NNODES, blk, 0, stream>>>(row_ptr, col_src, el, er, h_bf, b1,
                                            nullptr, o1_bf);

    // ---- layer 2 ----
    mfma_gemm_attn<64><<<gb, blk, 0, stream>>>(o1_bf, W2T, al2, ar2, h_bf, el, er, NNODES);
    gat_edge_v5<<<NNODES, blk, 0, stream>>>(row_ptr, col_src, el, er, h_bf, b2,
                                            out2_f, o2_bf);

    // ---- MLP (f32, fused BN partials) ----
    gemm_tile<64,true,true><<<dim3((MLP_HID + 63) / 64, gb), blk, 0, stream>>>(
        out2_f, Wm1, bm1, z, bn_sum, bn_sumsq, NNODES, MLP_HID);

    bn_final<<<1, 256, 0, stream>>>(bn_sum, bn_sumsq, gamma, beta, bn_scale, bn_shift, NNODES);
    mlp2<<<(NNODES * 64 + 255) / 256, blk, 0, stream>>>(
        z, bn_scale, bn_shift, Wm2, bm2, out, NNODES);
}

// Round 10
// 378.344 us; speedup vs baseline: 1.2725x; 1.1296x over previous
//
#include <hip/hip_runtime.h>
#include <hip/hip_bf16.h>

#define NNODES 50000
#define MLP_HID 200
#define NB_SCAN 196   // ceil(NNODES/256)
#define CAP 128       // per-node edge cache (mean degree ~17)

// init mega-kernel block ranges
#define NB_CONV 6250          // N*128/4/256
#define NB_W1   256
#define NB_W2   256
#define NB_ZC   196
#define INIT_BLOCKS (NB_CONV + NB_W1 + NB_W2 + NB_ZC + 1)

typedef __attribute__((ext_vector_type(8))) short bf16x8;
typedef __attribute__((ext_vector_type(4))) float f32x4;

__device__ __forceinline__ unsigned short f2bf(float x){
    unsigned u = __float_as_uint(x);
    unsigned r = (u + 0x7fffu + ((u >> 16) & 1u)) >> 16;
    return (unsigned short)r;
}
__device__ __forceinline__ float bflo(unsigned u){ return __uint_as_float(u << 16); }
__device__ __forceinline__ float bfhi(unsigned u){ return __uint_as_float(u & 0xffff0000u); }

// ---------------- init: feat->bf16, W1T, W2T, zero cnt & bn accumulators -----
__global__ __launch_bounds__(256) void init_all(
    const float* __restrict__ feat, unsigned short* __restrict__ featbf,
    const float* __restrict__ W1, unsigned short* __restrict__ W1T,
    const float* __restrict__ W2, unsigned short* __restrict__ W2T,
    int* __restrict__ cnt, float* __restrict__ bn_acc /*400 floats*/)
{
    const int b = blockIdx.x, tid = threadIdx.x;
    if (b < NB_CONV){
        long i = ((long)b * 256 + tid) * 4;
        float4 v = *(const float4*)&feat[i];
        ushort4 p;
        p.x = f2bf(v.x); p.y = f2bf(v.y); p.z = f2bf(v.z); p.w = f2bf(v.w);
        *(ushort4*)&featbf[i] = p;
    } else if (b < NB_CONV + NB_W1){
        int c = b - NB_CONV;
        if (tid < 128) W1T[(size_t)c * 128 + tid] = f2bf(W1[(size_t)tid * 256 + c]);
    } else if (b < NB_CONV + NB_W1 + NB_W2){
        int c = b - NB_CONV - NB_W1;
        if (tid < 64) W2T[(size_t)c * 64 + tid] = f2bf(W2[(size_t)tid * 256 + c]);
    } else if (b < NB_CONV + NB_W1 + NB_W2 + NB_ZC){
        int i = (b - NB_CONV - NB_W1 - NB_W2) * 256 + tid;
        if (i < NNODES) cnt[i] = 0;
    } else {
        if (tid < 2 * MLP_HID - 256) bn_acc[256 + tid] = 0.f;
        bn_acc[tid] = 0.f;
    }
}

// ---------------- MFMA GEMM + attn-dot epilogue ------------------------------
template<int K>
__global__ __launch_bounds__(256) void mfma_gemm_attn(
    const unsigned short* __restrict__ Abf,
    const unsigned short* __restrict__ WT,
    const float* __restrict__ al, const float* __restrict__ ar,
    unsigned short* __restrict__ hb,
    float* __restrict__ el, float* __restrict__ er, int M)
{
    const int wv = threadIdx.x >> 6, lane = threadIdx.x & 63;
    const int r0 = blockIdx.x * 64 + wv * 16;
    const int l15 = lane & 15, ks = lane >> 4;

    f32x4 acc[16];
    #pragma unroll
    for (int nt = 0; nt < 16; nt++)
        #pragma unroll
        for (int q = 0; q < 4; q++) acc[nt][q] = 0.f;

    const int arow = min(r0 + l15, M - 1);
    const unsigned short* aptr = Abf + (size_t)arow * K + ks * 8;
    const unsigned short* bptr = WT + (size_t)l15 * K + ks * 8;

    #pragma unroll
    for (int k0 = 0; k0 < K; k0 += 32){
        bf16x8 a = *(const bf16x8*)(aptr + k0);
        #pragma unroll
        for (int nt = 0; nt < 16; nt++){
            bf16x8 b = *(const bf16x8*)(bptr + (size_t)nt * 16 * K + k0);
            acc[nt] = __builtin_amdgcn_mfma_f32_16x16x32_bf16(a, b, acc[nt], 0, 0, 0);
        }
    }

    float elv[4][4], erv[4][4];
    #pragma unroll
    for (int r = 0; r < 4; r++)
        #pragma unroll
        for (int hh = 0; hh < 4; hh++){ elv[r][hh] = 0.f; erv[r][hh] = 0.f; }

    #pragma unroll
    for (int nt = 0; nt < 16; nt++){
        int col = nt * 16 + l15;
        float alv = al[col], arv = ar[col];
        #pragma unroll
        for (int reg = 0; reg < 4; reg++){
            elv[reg][nt >> 2] = fmaf(acc[nt][reg], alv, elv[reg][nt >> 2]);
            erv[reg][nt >> 2] = fmaf(acc[nt][reg], arv, erv[reg][nt >> 2]);
        }
    }
    #pragma unroll
    for (int o = 8; o > 0; o >>= 1){
        #pragma unroll
        for (int reg = 0; reg < 4; reg++)
            #pragma unroll
            for (int hh = 0; hh < 4; hh++){
                elv[reg][hh] += __shfl_xor(elv[reg][hh], o);
                erv[reg][hh] += __shfl_xor(erv[reg][hh], o);
            }
    }
    if (l15 == 0){
        #pragma unroll
        for (int reg = 0; reg < 4; reg++){
            int r = r0 + ks * 4 + reg;
            if (r < M){
                #pragma unroll
                for (int hh = 0; hh < 4; hh++){
                    el[r * 4 + hh] = elv[reg][hh];
                    er[r * 4 + hh] = erv[reg][hh];
                }
            }
        }
    }

    __shared__ __align__(16) unsigned short hbuf[4][16][264];
    #pragma unroll
    for (int nt = 0; nt < 16; nt++)
        #pragma unroll
        for (int reg = 0; reg < 4; reg++)
            hbuf[wv][ks * 4 + reg][nt * 16 + l15] = f2bf(acc[nt][reg]);
    #pragma unroll
    for (int t = 0; t < 8; t++){
        int chunk = t * 64 + lane;
        int rr = chunk >> 5;
        int cc = (chunk & 31) * 8;
        int r = r0 + rr;
        if (r < M){
            uint4 v = *(const uint4*)&hbuf[wv][rr][cc];
            *(uint4*)&hb[(size_t)r * 256 + cc] = v;
        }
    }
}

// ---------------- f32 GEMM (MLP layer): +bias +relu, fused BN partials -------
template<int KT, bool RELU, bool BN>
__global__ __launch_bounds__(256) void gemm_tile(const float* __restrict__ A,
                                                 const float* __restrict__ B,
                                                 const float* __restrict__ bias,
                                                 float* __restrict__ C,
                                                 float* __restrict__ bn_sum,
                                                 float* __restrict__ bn_sumsq,
                                                 int M, int Nc){
    __shared__ float As[16][64];
    __shared__ float Bs[16][64];
    __shared__ float bnred[16][64];
    const int tid = threadIdx.x;
    const int tx = tid & 15, ty = tid >> 4;
    const int r0 = blockIdx.y * 64, c0 = blockIdx.x * 64;
    float acc[4][4] = {};
    const int lr  = tid >> 2,  lk4 = (tid & 3) * 4;
    const int bk  = tid >> 4,  bc4 = (tid & 15) * 4;

    for (int k0 = 0; k0 < KT; k0 += 16){
        float4 av = make_float4(0.f,0.f,0.f,0.f);
        if (r0 + lr < M) av = *(const float4*)&A[(size_t)(r0 + lr) * KT + k0 + lk4];
        As[lk4+0][lr] = av.x; As[lk4+1][lr] = av.y;
        As[lk4+2][lr] = av.z; As[lk4+3][lr] = av.w;

        if (c0 + bc4 + 3 < Nc){
            float4 bv = *(const float4*)&B[(size_t)(k0 + bk) * Nc + c0 + bc4];
            Bs[bk][bc4+0] = bv.x; Bs[bk][bc4+1] = bv.y;
            Bs[bk][bc4+2] = bv.z; Bs[bk][bc4+3] = bv.w;
        } else {
            #pragma unroll
            for (int j = 0; j < 4; j++){
                int c = c0 + bc4 + j;
                Bs[bk][bc4+j] = (c < Nc) ? B[(size_t)(k0 + bk) * Nc + c] : 0.f;
            }
        }
        __syncthreads();
        #pragma unroll
        for (int kk = 0; kk < 16; kk++){
            float4 a = *(const float4*)&As[kk][ty*4];
            float4 b = *(const float4*)&Bs[kk][tx*4];
            float arr[4] = {a.x,a.y,a.z,a.w};
            float brr[4] = {b.x,b.y,b.z,b.w};
            #pragma unroll
            for (int i = 0; i < 4; i++)
                #pragma unroll
                for (int j = 0; j < 4; j++)
                    acc[i][j] = fmaf(arr[i], brr[j], acc[i][j]);
        }
        __syncthreads();
    }

    float cs[4] = {0,0,0,0}, css[4] = {0,0,0,0};
    #pragma unroll
    for (int i = 0; i < 4; i++){
        int r = r0 + ty*4 + i;
        bool rok = r < M;
        #pragma unroll
        for (int j = 0; j < 4; j++){
            int c = c0 + tx*4 + j;
            if (c >= Nc) continue;
            float v = acc[i][j];
            if (bias) v += bias[c];
            if (RELU) v = fmaxf(v, 0.f);
            if (rok){
                C[(size_t)r * Nc + c] = v;
                if (BN){ cs[j] += v; css[j] += v * v; }
            }
        }
    }
    if (BN){
        #pragma unroll
        for (int j = 0; j < 4; j++) bnred[ty][tx*4+j] = cs[j];
        __syncthreads();
        if (tid < 64){
            float s = 0.f;
            #pragma unroll
            for (int t = 0; t < 16; t++) s += bnred[t][tid];
            if (c0 + tid < Nc) atomicAdd(&bn_sum[c0 + tid], s);
        }
        __syncthreads();
        #pragma unroll
        for (int j = 0; j < 4; j++) bnred[ty][tx*4+j] = css[j];
        __syncthreads();
        if (tid < 64){
            float s = 0.f;
            #pragma unroll
            for (int t = 0; t < 16; t++) s += bnred[t][tid];
            if (c0 + tid < Nc) atomicAdd(&bn_sumsq[c0 + tid], s);
        }
    }
}

// ---------------- CSR build (hierarchical scan) ----------------
__global__ __launch_bounds__(256) void csr_count(const int* __restrict__ dst,
                                                 int* __restrict__ cnt, int E){
    int e = blockIdx.x * blockDim.x + threadIdx.x;
    if (e < E) atomicAdd(&cnt[dst[e]], 1);
}

__global__ __launch_bounds__(256) void csr_bsum(const int* __restrict__ cnt,
                                                int* __restrict__ bsum){
    __shared__ int red[256];
    int i = blockIdx.x * 256 + threadIdx.x;
    red[threadIdx.x] = (i < NNODES) ? cnt[i] : 0;
    __syncthreads();
    for (int off = 128; off > 0; off >>= 1){
        if (threadIdx.x < off) red[threadIdx.x] += red[threadIdx.x + off];
        __syncthreads();
    }
    if (threadIdx.x == 0) bsum[blockIdx.x] = red[0];
}

__global__ __launch_bounds__(256) void csr_bscan(const int* __restrict__ bsum,
                                                 int* __restrict__ boff){
    __shared__ int part[256];
    int t = threadIdx.x;
    int v = (t < NB_SCAN) ? bsum[t] : 0;
    part[t] = v;
    __syncthreads();
    for (int off = 1; off < 256; off <<= 1){
        int u = (t >= off) ? part[t - off] : 0;
        __syncthreads();
        part[t] += u;
        __syncthreads();
    }
    if (t < NB_SCAN) boff[t] = part[t] - v;
}

__global__ __launch_bounds__(256) void csr_fill(const int* __restrict__ cnt,
                                                const int* __restrict__ boff,
                                                int* __restrict__ row_ptr,
                                                int* __restrict__ cursor){
    __shared__ int part[256];
    int b = blockIdx.x, t = threadIdx.x;
    int i = b * 256 + t;
    int c = (i < NNODES) ? cnt[i] : 0;
    part[t] = c;
    __syncthreads();
    for (int off = 1; off < 256; off <<= 1){
        int u = (t >= off) ? part[t - off] : 0;
        __syncthreads();
        part[t] += u;
        __syncthreads();
    }
    int excl = part[t] - c + boff[b];
    if (i < NNODES){ row_ptr[i] = excl; cursor[i] = excl; }
    if (i == NNODES - 1) row_ptr[NNODES] = excl + c;
}

__global__ __launch_bounds__(256) void csr_scatter(const int* __restrict__ src,
                                                   const int* __restrict__ dst,
                                                   int* __restrict__ cursor,
                                                   int* __restrict__ col_src, int E){
    int e = blockIdx.x * blockDim.x + threadIdx.x;
    if (e >= E) return;
    int pos = atomicAdd(&cursor[dst[e]], 1);
    col_src[pos] = src[e];
}

// ---------------- edge kernel v6: one wave per node --------------------------
// Mean degree ~17 -> wave-sized work. No __syncthreads; per-wave LDS cache
// (conflict-free padded rows); softmax sums via 64-lane butterfly; gather:
// 2 half-wave slots x 32 lanes x 16B = one 512B h-row per slot-edge.
__global__ __launch_bounds__(256) void gat_edge_v6(
    const int* __restrict__ row_ptr, const int* __restrict__ col_src,
    const float* __restrict__ el, const float* __restrict__ er,
    const unsigned short* __restrict__ hb, const float* __restrict__ bias,
    float* __restrict__ out_f, unsigned short* __restrict__ out_b, int N)
{
    __shared__ float s_w[4][4][132];   // [wave][head][col] row stride 132 -> conflict-free
    __shared__ int   s_idx[4][CAP];

    const int wv = threadIdx.x >> 6;
    const int lane = threadIdx.x & 63;
    const int n = blockIdx.x * 4 + wv;
    if (n >= N) return;

    const int rs = row_ptr[n], re = row_ptr[n + 1];
    const int K = re - rs;
    const float4 ern = *(const float4*)&er[n * 4];
    float (*sw)[132] = s_w[wv];
    int* sidx = s_idx[wv];

    // phase 1: exp weights (max-free: |e| bounded), cache first CAP, sums
    float ls0 = 0.f, ls1 = 0.f, ls2 = 0.f, ls3 = 0.f;
    for (int k = lane; k < K; k += 64){
        int s = col_src[rs + k];
        float4 e4 = *(const float4*)&el[s * 4];
        float e0 = e4.x + ern.x; e0 = (e0 >= 0.f) ? e0 : 0.2f * e0;
        float e1 = e4.y + ern.y; e1 = (e1 >= 0.f) ? e1 : 0.2f * e1;
        float e2 = e4.z + ern.z; e2 = (e2 >= 0.f) ? e2 : 0.2f * e2;
        float e3 = e4.w + ern.w; e3 = (e3 >= 0.f) ? e3 : 0.2f * e3;
        float w0 = __expf(e0), w1 = __expf(e1), w2 = __expf(e2), w3 = __expf(e3);
        if (k < CAP){
            sidx[k] = s;
            sw[0][k] = w0; sw[1][k] = w1; sw[2][k] = w2; sw[3][k] = w3;
        }
        ls0 += w0; ls1 += w1; ls2 += w2; ls3 += w3;
    }
    #pragma unroll
    for (int o = 32; o > 0; o >>= 1){
        ls0 += __shfl_xor(ls0, o); ls1 += __shfl_xor(ls1, o);
        ls2 += __shfl_xor(ls2, o); ls3 += __shfl_xor(ls3, o);
    }
    // every lane now has all four sums
    const int slot = lane >> 5;           // 0/1 half-wave
    const int c8   = (lane & 31) * 8;     // covers head*64 + dim0
    const int hc   = c8 >> 6;
    const float invh = 1.f / (hc == 0 ? ls0 : hc == 1 ? ls1 : hc == 2 ? ls2 : ls3);

    // phase 2: weighted gather, 2 edges in flight per wave
    float acc[8];
    #pragma unroll
    for (int q = 0; q < 8; q++) acc[q] = 0.f;

    for (int base = 0; base < K; base += CAP){
        if (base > 0){                    // rare refill (K > CAP)
            for (int k = base + lane; k < min(K, base + CAP); k += 64){
                int s = col_src[rs + k];
                float4 e4 = *(const float4*)&el[s * 4];
                float e0 = e4.x + ern.x; e0 = (e0 >= 0.f) ? e0 : 0.2f * e0;
                float e1 = e4.y + ern.y; e1 = (e1 >= 0.f) ? e1 : 0.2f * e1;
                float e2 = e4.z + ern.z; e2 = (e2 >= 0.f) ? e2 : 0.2f * e2;
                float e3 = e4.w + ern.w; e3 = (e3 >= 0.f) ? e3 : 0.2f * e3;
                int kk = k - base;
                sidx[kk] = s;
                sw[0][kk] = __expf(e0); sw[1][kk] = __expf(e1);
                sw[2][kk] = __expf(e2); sw[3][kk] = __expf(e3);
            }
        }
        const int rem = min(CAP, K - base);
        int j = slot;
        for (; j + 2 < rem; j += 4){
            int   sA = sidx[j],     sB = sidx[j + 2];
            float wA = sw[hc][j],   wB = sw[hc][j + 2];
            uint4 vA = *(const uint4*)&hb[(size_t)sA * 256 + c8];
            uint4 vB = *(const uint4*)&hb[(size_t)sB * 256 + c8];
            acc[0] = fmaf(wA, bflo(vA.x), acc[0]);
            acc[1] = fmaf(wA, bfhi(vA.x), acc[1]);
            acc[2] = fmaf(wA, bflo(vA.y), acc[2]);
            acc[3] = fmaf(wA, bfhi(vA.y), acc[3]);
            acc[4] = fmaf(wA, bflo(vA.z), acc[4]);
            acc[5] = fmaf(wA, bfhi(vA.z), acc[5]);
            acc[6] = fmaf(wA, bflo(vA.w), acc[6]);
            acc[7] = fmaf(wA, bfhi(vA.w), acc[7]);
            acc[0] = fmaf(wB, bflo(vB.x), acc[0]);
            acc[1] = fmaf(wB, bfhi(vB.x), acc[1]);
            acc[2] = fmaf(wB, bflo(vB.y), acc[2]);
            acc[3] = fmaf(wB, bfhi(vB.y), acc[3]);
            acc[4] = fmaf(wB, bflo(vB.z), acc[4]);
            acc[5] = fmaf(wB, bfhi(vB.z), acc[5]);
            acc[6] = fmaf(wB, bflo(vB.w), acc[6]);
            acc[7] = fmaf(wB, bfhi(vB.w), acc[7]);
        }
        if (j < rem){
            int   sA = sidx[j];
            float wA = sw[hc][j];
            uint4 vA = *(const uint4*)&hb[(size_t)sA * 256 + c8];
            acc[0] = fmaf(wA, bflo(vA.x), acc[0]);
            acc[1] = fmaf(wA, bfhi(vA.x), acc[1]);
            acc[2] = fmaf(wA, bflo(vA.y), acc[2]);
            acc[3] = fmaf(wA, bfhi(vA.y), acc[3]);
            acc[4] = fmaf(wA, bflo(vA.z), acc[4]);
            acc[5] = fmaf(wA, bfhi(vA.z), acc[5]);
            acc[6] = fmaf(wA, bflo(vA.w), acc[6]);
            acc[7] = fmaf(wA, bfhi(vA.w), acc[7]);
        }
    }

    // normalize + slot reduce + bias/relu + head mean (all in-wave)
    #pragma unroll
    for (int q = 0; q < 8; q++){
        acc[q] *= invh;
        acc[q] += __shfl_xor(acc[q], 32);
        acc[q] = fmaxf(acc[q] + bias[c8 + q], 0.f);
        acc[q] += __shfl_xor(acc[q], 8);
        acc[q] += __shfl_xor(acc[q], 16);
        acc[q] *= 0.25f;
    }
    if (lane < 8){
        uint4 pb;
        pb.x = (unsigned)f2bf(acc[0]) | ((unsigned)f2bf(acc[1]) << 16);
        pb.y = (unsigned)f2bf(acc[2]) | ((unsigned)f2bf(acc[3]) << 16);
        pb.z = (unsigned)f2bf(acc[4]) | ((unsigned)f2bf(acc[5]) << 16);
        pb.w = (unsigned)f2bf(acc[6]) | ((unsigned)f2bf(acc[7]) << 16);
        *(uint4*)&out_b[(size_t)n * 64 + lane * 8] = pb;
        if (out_f){
            *(float4*)&out_f[(size_t)n * 64 + lane * 8]     = make_float4(acc[0], acc[1], acc[2], acc[3]);
            *(float4*)&out_f[(size_t)n * 64 + lane * 8 + 4] = make_float4(acc[4], acc[5], acc[6], acc[7]);
        }
    }
}

// ---------------- final linear (BN scale/shift computed inline) --------------
__global__ __launch_bounds__(256) void mlp2(const float* __restrict__ z,
                                            const float* __restrict__ bn_sum,
                                            const float* __restrict__ bn_sumsq,
                                            const float* __restrict__ gamma,
                                            const float* __restrict__ beta,
                                            const float* __restrict__ Wm2,
                                            const float* __restrict__ bm2,
                                            float* __restrict__ out,
                                            int Nrows){
    __shared__ float s_scale[MLP_HID], s_shift[MLP_HID];
    const int tid = threadIdx.x;
    if (tid < MLP_HID){
        float inv = 1.f / (float)Nrows;
        float mu = bn_sum[tid] * inv;
        float var = bn_sumsq[tid] * inv - mu * mu;
        float rstd = rsqrtf(var + 1e-5f);
        float sc = rstd * gamma[tid];
        s_scale[tid] = sc;
        s_shift[tid] = beta[tid] - mu * sc;
    }
    __syncthreads();
    int n = (blockIdx.x * 256 + tid) >> 6;
    if (n >= Nrows) return;
    int lane = tid & 63;
    float a0 = 0.f, a1 = 0.f;
    for (int k = lane; k < MLP_HID; k += 64){
        float zn = z[(size_t)n * MLP_HID + k] * s_scale[k] + s_shift[k];
        a0 = fmaf(zn, Wm2[k * 2 + 0], a0);
        a1 = fmaf(zn, Wm2[k * 2 + 1], a1);
    }
    #pragma unroll
    for (int o = 32; o > 0; o >>= 1){
        a0 += __shfl_xor(a0, o);
        a1 += __shfl_xor(a1, o);
    }
    if (lane == 0){
        out[n * 2 + 0] = a0 + bm2[0];
        out[n * 2 + 1] = a1 + bm2[1];
    }
}

extern "C" void kernel_launch(void* const* d_in, const int* in_sizes, int n_in,
                              void* d_out, int out_size, void* d_ws, size_t ws_size,
                              hipStream_t stream) {
    const float* feat  = (const float*)d_in[0];
    const int*   src   = (const int*)  d_in[1];
    const int*   dst   = (const int*)  d_in[2];
    const float* W1    = (const float*)d_in[3];
    const float* al1   = (const float*)d_in[4];
    const float* ar1   = (const float*)d_in[5];
    const float* b1    = (const float*)d_in[6];
    const float* W2    = (const float*)d_in[7];
    const float* al2   = (const float*)d_in[8];
    const float* ar2   = (const float*)d_in[9];
    const float* b2    = (const float*)d_in[10];
    const float* Wm1   = (const float*)d_in[11];
    const float* bm1   = (const float*)d_in[12];
    const float* gamma = (const float*)d_in[13];
    const float* beta  = (const float*)d_in[14];
    const float* Wm2   = (const float*)d_in[15];
    const float* bm2   = (const float*)d_in[16];
    const int E = in_sizes[1];
    float* out = (float*)d_out;

    // ---- workspace layout ----
    unsigned short* h_bf   = (unsigned short*)d_ws;                 // N*256 bf16
    unsigned short* featbf = h_bf   + (size_t)NNODES * 256;         // N*128 bf16 (dead after L1 gemm)
    unsigned short* o1_bf  = featbf + (size_t)NNODES * 128;         // N*64 bf16
    unsigned short* o2_bf  = o1_bf  + (size_t)NNODES * 64;          // N*64 bf16
    unsigned short* W1T    = o2_bf  + (size_t)NNODES * 64;          // 256*128
    unsigned short* W2T    = W1T + 256 * 128;                       // 256*64
    float* z      = (float*)(W2T + 256 * 64);                       // N*200 f32
    float* el     = z      + (size_t)NNODES * MLP_HID;              // N*4
    float* er     = el     + (size_t)NNODES * 4;                    // N*4
    float* bn_sum   = er + (size_t)NNODES * 4;                      // 200
    float* bn_sumsq = bn_sum + MLP_HID;                             // 200
    int* cnt      = (int*)(bn_sumsq + MLP_HID);                     // N
    int* row_ptr  = cnt + NNODES;                                   // N+1
    int* cursor   = row_ptr + NNODES + 1;                           // N
    int* bsum     = cursor + NNODES;                                // 256
    int* boff     = bsum + 256;                                     // 256
    int* col_src  = boff + 256;                                     // E
    float* out2_f = (float*)featbf;   // alias: featbf dead after layer-1 GEMM

    const dim3 blk(256);
    const int eg = (E + 255) / 256;
    const int gb = (NNODES + 63) / 64;
    const int ng4 = (NNODES + 3) / 4;       // wave-per-node edge grid

    // ---- init (conversions + zeroing) ----
    init_all<<<INIT_BLOCKS, blk, 0, stream>>>(feat, featbf, W1, W1T, W2, W2T,
                                              cnt, bn_sum);

    // ---- CSR build ----
    csr_count<<<eg, blk, 0, stream>>>(dst, cnt, E);
    csr_bsum<<<NB_SCAN, blk, 0, stream>>>(cnt, bsum);
    csr_bscan<<<1, blk, 0, stream>>>(bsum, boff);
    csr_fill<<<NB_SCAN, blk, 0, stream>>>(cnt, boff, row_ptr, cursor);
    csr_scatter<<<eg, blk, 0, stream>>>(src, dst, cursor, col_src, E);

    // ---- layer 1 ----
    mfma_gemm_attn<128><<<gb, blk, 0, stream>>>(featbf, W1T, al1, ar1, h_bf, el, er, NNODES);
    gat_edge_v6<<<ng4, blk, 0, stream>>>(row_ptr, col_src, el, er, h_bf, b1,
                                         nullptr, o1_bf, NNODES);

    // ---- layer 2 ----
    mfma_gemm_attn<64><<<gb, blk, 0, stream>>>(o1_bf, W2T, al2, ar2, h_bf, el, er, NNODES);
    gat_edge_v6<<<ng4, blk, 0, stream>>>(row_ptr, col_src, el, er, h_bf, b2,
                                         out2_f, o2_bf, NNODES);

    // ---- MLP (f32, fused BN partials) ----
    gemm_tile<64,true,true><<<dim3((MLP_HID + 63) / 64, gb), blk, 0, stream>>>(
        out2_f, Wm1, bm1, z, bn_sum, bn_sumsq, NNODES, MLP_HID);

    mlp2<<<(NNODES * 64 + 255) / 256, blk, 0, stream>>>(
        z, bn_sum, bn_sumsq, gamma, beta, Wm2, bm2, out, NNODES);
}

// Round 11
// 372.281 us; speedup vs baseline: 1.2932x; 1.0163x over previous
//
#include <hip/hip_runtime.h>
#include <hip/hip_bf16.h>

#define NNODES 50000
#define MLP_HID 200
#define NB_SCAN 196   // ceil(NNODES/256)
#define CAP 128       // per-node edge cache (mean degree ~17)

// init kernel block ranges (feat conversion removed: layer-1 GEMM reads f32)
#define NB_W1   256
#define NB_W2   256
#define NB_ZC   196
#define INIT_BLOCKS (NB_W1 + NB_W2 + NB_ZC + 1)

typedef __attribute__((ext_vector_type(8))) short bf16x8;
typedef __attribute__((ext_vector_type(4))) float f32x4;

__device__ __forceinline__ unsigned short f2bf(float x){
    unsigned u = __float_as_uint(x);
    unsigned r = (u + 0x7fffu + ((u >> 16) & 1u)) >> 16;
    return (unsigned short)r;
}
__device__ __forceinline__ float bflo(unsigned u){ return __uint_as_float(u << 16); }
__device__ __forceinline__ float bfhi(unsigned u){ return __uint_as_float(u & 0xffff0000u); }

// ---------------- init: W1T, W2T, zero cnt & bn accumulators -----------------
__global__ __launch_bounds__(256) void init_all(
    const float* __restrict__ W1, unsigned short* __restrict__ W1T,
    const float* __restrict__ W2, unsigned short* __restrict__ W2T,
    int* __restrict__ cnt, float* __restrict__ bn_acc /*400 floats*/)
{
    const int b = blockIdx.x, tid = threadIdx.x;
    if (b < NB_W1){
        int c = b;
        if (tid < 128) W1T[(size_t)c * 128 + tid] = f2bf(W1[(size_t)tid * 256 + c]);
    } else if (b < NB_W1 + NB_W2){
        int c = b - NB_W1;
        if (tid < 64) W2T[(size_t)c * 64 + tid] = f2bf(W2[(size_t)tid * 256 + c]);
    } else if (b < NB_W1 + NB_W2 + NB_ZC){
        int i = (b - NB_W1 - NB_W2) * 256 + tid;
        if (i < NNODES) cnt[i] = 0;
    } else {
        if (tid < 2 * MLP_HID - 256) bn_acc[256 + tid] = 0.f;
        bn_acc[tid] = 0.f;
    }
}

// ---------------- MFMA GEMM + attn-dot epilogue ------------------------------
// F32IN: A is f32 (converted to bf16 in-register, same rounding as init path).
template<int K, bool F32IN>
__global__ __launch_bounds__(256) void mfma_gemm_attn(
    const void* __restrict__ Aptr,
    const unsigned short* __restrict__ WT,
    const float* __restrict__ al, const float* __restrict__ ar,
    unsigned short* __restrict__ hb,
    float* __restrict__ el, float* __restrict__ er, int M)
{
    const int wv = threadIdx.x >> 6, lane = threadIdx.x & 63;
    const int r0 = blockIdx.x * 64 + wv * 16;
    const int l15 = lane & 15, ks = lane >> 4;

    f32x4 acc[16];
    #pragma unroll
    for (int nt = 0; nt < 16; nt++)
        #pragma unroll
        for (int q = 0; q < 4; q++) acc[nt][q] = 0.f;

    const int arow = min(r0 + l15, M - 1);
    const unsigned short* aptr_b = (const unsigned short*)Aptr + (size_t)arow * K + ks * 8;
    const float*          aptr_f = (const float*)Aptr          + (size_t)arow * K + ks * 8;
    const unsigned short* bptr = WT + (size_t)l15 * K + ks * 8;

    #pragma unroll
    for (int k0 = 0; k0 < K; k0 += 32){
        bf16x8 a;
        if (F32IN){
            float4 f0 = *(const float4*)(aptr_f + k0);
            float4 f1 = *(const float4*)(aptr_f + k0 + 4);
            a[0] = (short)f2bf(f0.x); a[1] = (short)f2bf(f0.y);
            a[2] = (short)f2bf(f0.z); a[3] = (short)f2bf(f0.w);
            a[4] = (short)f2bf(f1.x); a[5] = (short)f2bf(f1.y);
            a[6] = (short)f2bf(f1.z); a[7] = (short)f2bf(f1.w);
        } else {
            a = *(const bf16x8*)(aptr_b + k0);
        }
        #pragma unroll
        for (int nt = 0; nt < 16; nt++){
            bf16x8 b = *(const bf16x8*)(bptr + (size_t)nt * 16 * K + k0);
            acc[nt] = __builtin_amdgcn_mfma_f32_16x16x32_bf16(a, b, acc[nt], 0, 0, 0);
        }
    }

    float elv[4][4], erv[4][4];
    #pragma unroll
    for (int r = 0; r < 4; r++)
        #pragma unroll
        for (int hh = 0; hh < 4; hh++){ elv[r][hh] = 0.f; erv[r][hh] = 0.f; }

    #pragma unroll
    for (int nt = 0; nt < 16; nt++){
        int col = nt * 16 + l15;
        float alv = al[col], arv = ar[col];
        #pragma unroll
        for (int reg = 0; reg < 4; reg++){
            elv[reg][nt >> 2] = fmaf(acc[nt][reg], alv, elv[reg][nt >> 2]);
            erv[reg][nt >> 2] = fmaf(acc[nt][reg], arv, erv[reg][nt >> 2]);
        }
    }
    #pragma unroll
    for (int o = 8; o > 0; o >>= 1){
        #pragma unroll
        for (int reg = 0; reg < 4; reg++)
            #pragma unroll
            for (int hh = 0; hh < 4; hh++){
                elv[reg][hh] += __shfl_xor(elv[reg][hh], o);
                erv[reg][hh] += __shfl_xor(erv[reg][hh], o);
            }
    }
    if (l15 == 0){
        #pragma unroll
        for (int reg = 0; reg < 4; reg++){
            int r = r0 + ks * 4 + reg;
            if (r < M){
                #pragma unroll
                for (int hh = 0; hh < 4; hh++){
                    el[r * 4 + hh] = elv[reg][hh];
                    er[r * 4 + hh] = erv[reg][hh];
                }
            }
        }
    }

    __shared__ __align__(16) unsigned short hbuf[4][16][264];
    #pragma unroll
    for (int nt = 0; nt < 16; nt++)
        #pragma unroll
        for (int reg = 0; reg < 4; reg++)
            hbuf[wv][ks * 4 + reg][nt * 16 + l15] = f2bf(acc[nt][reg]);
    #pragma unroll
    for (int t = 0; t < 8; t++){
        int chunk = t * 64 + lane;
        int rr = chunk >> 5;
        int cc = (chunk & 31) * 8;
        int r = r0 + rr;
        if (r < M){
            uint4 v = *(const uint4*)&hbuf[wv][rr][cc];
            *(uint4*)&hb[(size_t)r * 256 + cc] = v;
        }
    }
}

// ---------------- f32 GEMM (MLP layer): +bias +relu, fused BN partials -------
template<int KT, bool RELU, bool BN>
__global__ __launch_bounds__(256) void gemm_tile(const float* __restrict__ A,
                                                 const float* __restrict__ B,
                                                 const float* __restrict__ bias,
                                                 float* __restrict__ C,
                                                 float* __restrict__ bn_sum,
                                                 float* __restrict__ bn_sumsq,
                                                 int M, int Nc){
    __shared__ float As[16][64];
    __shared__ float Bs[16][64];
    __shared__ float bnred[16][64];
    const int tid = threadIdx.x;
    const int tx = tid & 15, ty = tid >> 4;
    const int r0 = blockIdx.y * 64, c0 = blockIdx.x * 64;
    float acc[4][4] = {};
    const int lr  = tid >> 2,  lk4 = (tid & 3) * 4;
    const int bk  = tid >> 4,  bc4 = (tid & 15) * 4;

    for (int k0 = 0; k0 < KT; k0 += 16){
        float4 av = make_float4(0.f,0.f,0.f,0.f);
        if (r0 + lr < M) av = *(const float4*)&A[(size_t)(r0 + lr) * KT + k0 + lk4];
        As[lk4+0][lr] = av.x; As[lk4+1][lr] = av.y;
        As[lk4+2][lr] = av.z; As[lk4+3][lr] = av.w;

        if (c0 + bc4 + 3 < Nc){
            float4 bv = *(const float4*)&B[(size_t)(k0 + bk) * Nc + c0 + bc4];
            Bs[bk][bc4+0] = bv.x; Bs[bk][bc4+1] = bv.y;
            Bs[bk][bc4+2] = bv.z; Bs[bk][bc4+3] = bv.w;
        } else {
            #pragma unroll
            for (int j = 0; j < 4; j++){
                int c = c0 + bc4 + j;
                Bs[bk][bc4+j] = (c < Nc) ? B[(size_t)(k0 + bk) * Nc + c] : 0.f;
            }
        }
        __syncthreads();
        #pragma unroll
        for (int kk = 0; kk < 16; kk++){
            float4 a = *(const float4*)&As[kk][ty*4];
            float4 b = *(const float4*)&Bs[kk][tx*4];
            float arr[4] = {a.x,a.y,a.z,a.w};
            float brr[4] = {b.x,b.y,b.z,b.w};
            #pragma unroll
            for (int i = 0; i < 4; i++)
                #pragma unroll
                for (int j = 0; j < 4; j++)
                    acc[i][j] = fmaf(arr[i], brr[j], acc[i][j]);
        }
        __syncthreads();
    }

    float cs[4] = {0,0,0,0}, css[4] = {0,0,0,0};
    #pragma unroll
    for (int i = 0; i < 4; i++){
        int r = r0 + ty*4 + i;
        bool rok = r < M;
        #pragma unroll
        for (int j = 0; j < 4; j++){
            int c = c0 + tx*4 + j;
            if (c >= Nc) continue;
            float v = acc[i][j];
            if (bias) v += bias[c];
            if (RELU) v = fmaxf(v, 0.f);
            if (rok){
                C[(size_t)r * Nc + c] = v;
                if (BN){ cs[j] += v; css[j] += v * v; }
            }
        }
    }
    if (BN){
        #pragma unroll
        for (int j = 0; j < 4; j++) bnred[ty][tx*4+j] = cs[j];
        __syncthreads();
        if (tid < 64){
            float s = 0.f;
            #pragma unroll
            for (int t = 0; t < 16; t++) s += bnred[t][tid];
            if (c0 + tid < Nc) atomicAdd(&bn_sum[c0 + tid], s);
        }
        __syncthreads();
        #pragma unroll
        for (int j = 0; j < 4; j++) bnred[ty][tx*4+j] = css[j];
        __syncthreads();
        if (tid < 64){
            float s = 0.f;
            #pragma unroll
            for (int t = 0; t < 16; t++) s += bnred[t][tid];
            if (c0 + tid < Nc) atomicAdd(&bn_sumsq[c0 + tid], s);
        }
    }
}

// ---------------- CSR build (hierarchical scan) ----------------
__global__ __launch_bounds__(256) void csr_count(const int* __restrict__ dst,
                                                 int* __restrict__ cnt, int E){
    int e = blockIdx.x * blockDim.x + threadIdx.x;
    if (e < E) atomicAdd(&cnt[dst[e]], 1);
}

__global__ __launch_bounds__(256) void csr_bsum(const int* __restrict__ cnt,
                                                int* __restrict__ bsum){
    __shared__ int red[256];
    int i = blockIdx.x * 256 + threadIdx.x;
    red[threadIdx.x] = (i < NNODES) ? cnt[i] : 0;
    __syncthreads();
    for (int off = 128; off > 0; off >>= 1){
        if (threadIdx.x < off) red[threadIdx.x] += red[threadIdx.x + off];
        __syncthreads();
    }
    if (threadIdx.x == 0) bsum[blockIdx.x] = red[0];
}

__global__ __launch_bounds__(256) void csr_bscan(const int* __restrict__ bsum,
                                                 int* __restrict__ boff){
    __shared__ int part[256];
    int t = threadIdx.x;
    int v = (t < NB_SCAN) ? bsum[t] : 0;
    part[t] = v;
    __syncthreads();
    for (int off = 1; off < 256; off <<= 1){
        int u = (t >= off) ? part[t - off] : 0;
        __syncthreads();
        part[t] += u;
        __syncthreads();
    }
    if (t < NB_SCAN) boff[t] = part[t] - v;
}

__global__ __launch_bounds__(256) void csr_fill(const int* __restrict__ cnt,
                                                const int* __restrict__ boff,
                                                int* __restrict__ row_ptr,
                                                int* __restrict__ cursor){
    __shared__ int part[256];
    int b = blockIdx.x, t = threadIdx.x;
    int i = b * 256 + t;
    int c = (i < NNODES) ? cnt[i] : 0;
    part[t] = c;
    __syncthreads();
    for (int off = 1; off < 256; off <<= 1){
        int u = (t >= off) ? part[t - off] : 0;
        __syncthreads();
        part[t] += u;
        __syncthreads();
    }
    int excl = part[t] - c + boff[b];
    if (i < NNODES){ row_ptr[i] = excl; cursor[i] = excl; }
    if (i == NNODES - 1) row_ptr[NNODES] = excl + c;
}

__global__ __launch_bounds__(256) void csr_scatter(const int* __restrict__ src,
                                                   const int* __restrict__ dst,
                                                   int* __restrict__ cursor,
                                                   int* __restrict__ col_src, int E){
    int e = blockIdx.x * blockDim.x + threadIdx.x;
    if (e >= E) return;
    int pos = atomicAdd(&cursor[dst[e]], 1);
    col_src[pos] = src[e];
}

// ---------------- edge kernel v7: one wave per node, 4-deep gather -----------
// Clamped-index/zero-weight tail: no branchy tails, 4 independent 16B loads
// in flight per lane.
__global__ __launch_bounds__(256) void gat_edge_v7(
    const int* __restrict__ row_ptr, const int* __restrict__ col_src,
    const float* __restrict__ el, const float* __restrict__ er,
    const unsigned short* __restrict__ hb, const float* __restrict__ bias,
    float* __restrict__ out_f, unsigned short* __restrict__ out_b, int N)
{
    __shared__ float s_w[4][4][132];   // [wave][head][col] stride 132 -> conflict-free
    __shared__ int   s_idx[4][CAP];

    const int wv = threadIdx.x >> 6;
    const int lane = threadIdx.x & 63;
    const int n = blockIdx.x * 4 + wv;
    if (n >= N) return;

    const int rs = row_ptr[n], re = row_ptr[n + 1];
    const int K = re - rs;
    const float4 ern = *(const float4*)&er[n * 4];
    float (*sw)[132] = s_w[wv];
    int* sidx = s_idx[wv];

    // phase 1: exp weights (max-free: |e| bounded), cache first CAP, sums
    float ls0 = 0.f, ls1 = 0.f, ls2 = 0.f, ls3 = 0.f;
    for (int k = lane; k < K; k += 64){
        int s = col_src[rs + k];
        float4 e4 = *(const float4*)&el[s * 4];
        float e0 = e4.x + ern.x; e0 = (e0 >= 0.f) ? e0 : 0.2f * e0;
        float e1 = e4.y + ern.y; e1 = (e1 >= 0.f) ? e1 : 0.2f * e1;
        float e2 = e4.z + ern.z; e2 = (e2 >= 0.f) ? e2 : 0.2f * e2;
        float e3 = e4.w + ern.w; e3 = (e3 >= 0.f) ? e3 : 0.2f * e3;
        float w0 = __expf(e0), w1 = __expf(e1), w2 = __expf(e2), w3 = __expf(e3);
        if (k < CAP){
            sidx[k] = s;
            sw[0][k] = w0; sw[1][k] = w1; sw[2][k] = w2; sw[3][k] = w3;
        }
        ls0 += w0; ls1 += w1; ls2 += w2; ls3 += w3;
    }
    #pragma unroll
    for (int o = 32; o > 0; o >>= 1){
        ls0 += __shfl_xor(ls0, o); ls1 += __shfl_xor(ls1, o);
        ls2 += __shfl_xor(ls2, o); ls3 += __shfl_xor(ls3, o);
    }
    const int slot = lane >> 5;           // 0/1 half-wave
    const int c8   = (lane & 31) * 8;     // head*64 + dim0
    const int hc   = c8 >> 6;
    const float invh = 1.f / (hc == 0 ? ls0 : hc == 1 ? ls1 : hc == 2 ? ls2 : ls3);

    // phase 2: weighted gather, 4 edges in flight per half-wave
    float acc[8];
    #pragma unroll
    for (int q = 0; q < 8; q++) acc[q] = 0.f;

    for (int base = 0; base < K; base += CAP){
        if (base > 0){                    // rare refill (K > CAP)
            for (int k = base + lane; k < min(K, base + CAP); k += 64){
                int s = col_src[rs + k];
                float4 e4 = *(const float4*)&el[s * 4];
                float e0 = e4.x + ern.x; e0 = (e0 >= 0.f) ? e0 : 0.2f * e0;
                float e1 = e4.y + ern.y; e1 = (e1 >= 0.f) ? e1 : 0.2f * e1;
                float e2 = e4.z + ern.z; e2 = (e2 >= 0.f) ? e2 : 0.2f * e2;
                float e3 = e4.w + ern.w; e3 = (e3 >= 0.f) ? e3 : 0.2f * e3;
                int kk = k - base;
                sidx[kk] = s;
                sw[0][kk] = __expf(e0); sw[1][kk] = __expf(e1);
                sw[2][kk] = __expf(e2); sw[3][kk] = __expf(e3);
            }
        }
        const int rem = min(CAP, K - base);
        for (int j = slot; j < rem; j += 8){
            int   j1 = j + 2, j2 = j + 4, j3 = j + 6;
            int   jc1 = min(j1, rem - 1), jc2 = min(j2, rem - 1), jc3 = min(j3, rem - 1);
            float w0v = sw[hc][j];
            float w1v = (j1 < rem) ? sw[hc][j1] : 0.f;
            float w2v = (j2 < rem) ? sw[hc][j2] : 0.f;
            float w3v = (j3 < rem) ? sw[hc][j3] : 0.f;
            int   s0 = sidx[j], s1 = sidx[jc1], s2 = sidx[jc2], s3 = sidx[jc3];
            uint4 v0 = *(const uint4*)&hb[(size_t)s0 * 256 + c8];
            uint4 v1 = *(const uint4*)&hb[(size_t)s1 * 256 + c8];
            uint4 v2 = *(const uint4*)&hb[(size_t)s2 * 256 + c8];
            uint4 v3 = *(const uint4*)&hb[(size_t)s3 * 256 + c8];
            acc[0] = fmaf(w0v, bflo(v0.x), acc[0]); acc[1] = fmaf(w0v, bfhi(v0.x), acc[1]);
            acc[2] = fmaf(w0v, bflo(v0.y), acc[2]); acc[3] = fmaf(w0v, bfhi(v0.y), acc[3]);
            acc[4] = fmaf(w0v, bflo(v0.z), acc[4]); acc[5] = fmaf(w0v, bfhi(v0.z), acc[5]);
            acc[6] = fmaf(w0v, bflo(v0.w), acc[6]); acc[7] = fmaf(w0v, bfhi(v0.w), acc[7]);
            acc[0] = fmaf(w1v, bflo(v1.x), acc[0]); acc[1] = fmaf(w1v, bfhi(v1.x), acc[1]);
            acc[2] = fmaf(w1v, bflo(v1.y), acc[2]); acc[3] = fmaf(w1v, bfhi(v1.y), acc[3]);
            acc[4] = fmaf(w1v, bflo(v1.z), acc[4]); acc[5] = fmaf(w1v, bfhi(v1.z), acc[5]);
            acc[6] = fmaf(w1v, bflo(v1.w), acc[6]); acc[7] = fmaf(w1v, bfhi(v1.w), acc[7]);
            acc[0] = fmaf(w2v, bflo(v2.x), acc[0]); acc[1] = fmaf(w2v, bfhi(v2.x), acc[1]);
            acc[2] = fmaf(w2v, bflo(v2.y), acc[2]); acc[3] = fmaf(w2v, bfhi(v2.y), acc[3]);
            acc[4] = fmaf(w2v, bflo(v2.z), acc[4]); acc[5] = fmaf(w2v, bfhi(v2.z), acc[5]);
            acc[6] = fmaf(w2v, bflo(v2.w), acc[6]); acc[7] = fmaf(w2v, bfhi(v2.w), acc[7]);
            acc[0] = fmaf(w3v, bflo(v3.x), acc[0]); acc[1] = fmaf(w3v, bfhi(v3.x), acc[1]);
            acc[2] = fmaf(w3v, bflo(v3.y), acc[2]); acc[3] = fmaf(w3v, bfhi(v3.y), acc[3]);
            acc[4] = fmaf(w3v, bflo(v3.z), acc[4]); acc[5] = fmaf(w3v, bfhi(v3.z), acc[5]);
            acc[6] = fmaf(w3v, bflo(v3.w), acc[6]); acc[7] = fmaf(w3v, bfhi(v3.w), acc[7]);
        }
    }

    // normalize + slot reduce + bias/relu + head mean (all in-wave)
    #pragma unroll
    for (int q = 0; q < 8; q++){
        acc[q] *= invh;
        acc[q] += __shfl_xor(acc[q], 32);
        acc[q] = fmaxf(acc[q] + bias[c8 + q], 0.f);
        acc[q] += __shfl_xor(acc[q], 8);
        acc[q] += __shfl_xor(acc[q], 16);
        acc[q] *= 0.25f;
    }
    if (lane < 8){
        uint4 pb;
        pb.x = (unsigned)f2bf(acc[0]) | ((unsigned)f2bf(acc[1]) << 16);
        pb.y = (unsigned)f2bf(acc[2]) | ((unsigned)f2bf(acc[3]) << 16);
        pb.z = (unsigned)f2bf(acc[4]) | ((unsigned)f2bf(acc[5]) << 16);
        pb.w = (unsigned)f2bf(acc[6]) | ((unsigned)f2bf(acc[7]) << 16);
        *(uint4*)&out_b[(size_t)n * 64 + lane * 8] = pb;
        if (out_f){
            *(float4*)&out_f[(size_t)n * 64 + lane * 8]     = make_float4(acc[0], acc[1], acc[2], acc[3]);
            *(float4*)&out_f[(size_t)n * 64 + lane * 8 + 4] = make_float4(acc[4], acc[5], acc[6], acc[7]);
        }
    }
}

// ---------------- final linear (BN scale/shift computed inline) --------------
__global__ __launch_bounds__(256) void mlp2(const float* __restrict__ z,
                                            const float* __restrict__ bn_sum,
                                            const float* __restrict__ bn_sumsq,
                                            const float* __restrict__ gamma,
                                            const float* __restrict__ beta,
                                            const float* __restrict__ Wm2,
                                            const float* __restrict__ bm2,
                                            float* __restrict__ out,
                                            int Nrows){
    __shared__ float s_scale[MLP_HID], s_shift[MLP_HID];
    const int tid = threadIdx.x;
    if (tid < MLP_HID){
        float inv = 1.f / (float)Nrows;
        float mu = bn_sum[tid] * inv;
        float var = bn_sumsq[tid] * inv - mu * mu;
        float rstd = rsqrtf(var + 1e-5f);
        float sc = rstd * gamma[tid];
        s_scale[tid] = sc;
        s_shift[tid] = beta[tid] - mu * sc;
    }
    __syncthreads();
    int n = (blockIdx.x * 256 + tid) >> 6;
    if (n >= Nrows) return;
    int lane = tid & 63;
    float a0 = 0.f, a1 = 0.f;
    for (int k = lane; k < MLP_HID; k += 64){
        float zn = z[(size_t)n * MLP_HID + k] * s_scale[k] + s_shift[k];
        a0 = fmaf(zn, Wm2[k * 2 + 0], a0);
        a1 = fmaf(zn, Wm2[k * 2 + 1], a1);
    }
    #pragma unroll
    for (int o = 32; o > 0; o >>= 1){
        a0 += __shfl_xor(a0, o);
        a1 += __shfl_xor(a1, o);
    }
    if (lane == 0){
        out[n * 2 + 0] = a0 + bm2[0];
        out[n * 2 + 1] = a1 + bm2[1];
    }
}

extern "C" void kernel_launch(void* const* d_in, const int* in_sizes, int n_in,
                              void* d_out, int out_size, void* d_ws, size_t ws_size,
                              hipStream_t stream) {
    const float* feat  = (const float*)d_in[0];
    const int*   src   = (const int*)  d_in[1];
    const int*   dst   = (const int*)  d_in[2];
    const float* W1    = (const float*)d_in[3];
    const float* al1   = (const float*)d_in[4];
    const float* ar1   = (const float*)d_in[5];
    const float* b1    = (const float*)d_in[6];
    const float* W2    = (const float*)d_in[7];
    const float* al2   = (const float*)d_in[8];
    const float* ar2   = (const float*)d_in[9];
    const float* b2    = (const float*)d_in[10];
    const float* Wm1   = (const float*)d_in[11];
    const float* bm1   = (const float*)d_in[12];
    const float* gamma = (const float*)d_in[13];
    const float* beta  = (const float*)d_in[14];
    const float* Wm2   = (const float*)d_in[15];
    const float* bm2   = (const float*)d_in[16];
    const int E = in_sizes[1];
    float* out = (float*)d_out;

    // ---- workspace layout ----
    unsigned short* h_bf   = (unsigned short*)d_ws;                 // N*256 bf16
    unsigned short* o1_bf  = h_bf   + (size_t)NNODES * 256;         // N*64 bf16
    unsigned short* o2_bf  = o1_bf  + (size_t)NNODES * 64;          // N*64 bf16
    unsigned short* W1T    = o2_bf  + (size_t)NNODES * 64;          // 256*128
    unsigned short* W2T    = W1T + 256 * 128;                       // 256*64
    float* z      = (float*)(W2T + 256 * 64);                       // N*200 f32
    float* out2_f = z      + (size_t)NNODES * MLP_HID;              // N*64 f32
    float* el     = out2_f + (size_t)NNODES * 64;                   // N*4
    float* er     = el     + (size_t)NNODES * 4;                    // N*4
    float* bn_sum   = er + (size_t)NNODES * 4;                      // 200
    float* bn_sumsq = bn_sum + MLP_HID;                             // 200
    int* cnt      = (int*)(bn_sumsq + MLP_HID);                     // N
    int* row_ptr  = cnt + NNODES;                                   // N+1
    int* cursor   = row_ptr + NNODES + 1;                           // N
    int* bsum     = cursor + NNODES;                                // 256
    int* boff     = bsum + 256;                                     // 256
    int* col_src  = boff + 256;                                     // E

    const dim3 blk(256);
    const int eg = (E + 255) / 256;
    const int gb = (NNODES + 63) / 64;
    const int ng4 = (NNODES + 3) / 4;       // wave-per-node edge grid

    // ---- init (weight transposes + zeroing) ----
    init_all<<<INIT_BLOCKS, blk, 0, stream>>>(W1, W1T, W2, W2T, cnt, bn_sum);

    // ---- CSR build ----
    csr_count<<<eg, blk, 0, stream>>>(dst, cnt, E);
    csr_bsum<<<NB_SCAN, blk, 0, stream>>>(cnt, bsum);
    csr_bscan<<<1, blk, 0, stream>>>(bsum, boff);
    csr_fill<<<NB_SCAN, blk, 0, stream>>>(cnt, boff, row_ptr, cursor);
    csr_scatter<<<eg, blk, 0, stream>>>(src, dst, cursor, col_src, E);

    // ---- layer 1 (f32 feat read directly, in-register bf16 pack) ----
    mfma_gemm_attn<128, true><<<gb, blk, 0, stream>>>(feat, W1T, al1, ar1,
                                                      h_bf, el, er, NNODES);
    gat_edge_v7<<<ng4, blk, 0, stream>>>(row_ptr, col_src, el, er, h_bf, b1,
                                         nullptr, o1_bf, NNODES);

    // ---- layer 2 ----
    mfma_gemm_attn<64, false><<<gb, blk, 0, stream>>>(o1_bf, W2T, al2, ar2,
                                                      h_bf, el, er, NNODES);
    gat_edge_v7<<<ng4, blk, 0, stream>>>(row_ptr, col_src, el, er, h_bf, b2,
                                         out2_f, o2_bf, NNODES);

    // ---- MLP (f32, fused BN partials) ----
    gemm_tile<64,true,true><<<dim3((MLP_HID + 63) / 64, gb), blk, 0, stream>>>(
        out2_f, Wm1, bm1, z, bn_sum, bn_sumsq, NNODES, MLP_HID);

    mlp2<<<(NNODES * 64 + 255) / 256, blk, 0, stream>>>(
        z, bn_sum, bn_sumsq, gamma, beta, Wm2, bm2, out, NNODES);
}